// Round 16
// baseline (2105.562 us; speedup 1.0000x reference)
//
#include <hip/hip_runtime.h>

// GraphSAGE 2-layer (mean agg), N=100K, E=1.6M, 128->128->64, f32 in/out.
// R16: BUCKET-MAJOR aggregation. Buckets of 128 nodes (b=dst>>7, P=782).
// CSR reduced to bucket-sorted edge list bed[(src<<8)|dst&127]; aggregation is
// one block/bucket with f32 LDS accumulators (padded rows, bank-rotated
// ds_add_f32) streaming the bucket's edges -- k_bcsr and col[] deleted.
// Layer2 agg fused with +s2,relu. Persistent fused GEMM (R11/R15-proven).
// Overlays: s2f->aggb (tile-local rows); p8 standalone (bed lives to the end).

typedef __attribute__((ext_vector_type(8))) short short8;
typedef __attribute__((ext_vector_type(4))) float f32x4;
typedef __attribute__((ext_vector_type(2))) float f32x2;

__device__ __forceinline__ ushort f2bf(float f) {
  uint u = __float_as_uint(f);
  u += 0x7fffu + ((u >> 16) & 1u);  // round-to-nearest-even
  return (ushort)(u >> 16);
}

#define GLDS(src, dst)                                                        \
  __builtin_amdgcn_global_load_lds(                                           \
      (const __attribute__((address_space(1))) void*)(src),                   \
      (__attribute__((address_space(3))) void*)(dst), 16, 0, 0)

#define FENCE() asm volatile("" ::: "memory")
#define LGKM0() asm volatile("s_waitcnt lgkmcnt(0)" ::: "memory")

// ================= bucket build (128-node buckets) =================
__global__ __launch_bounds__(256) void k_bhist(const int* __restrict__ dst,
                                               int* __restrict__ bcnt, int E) {
  __shared__ int h[1024];
  int t = threadIdx.x;
  for (int i = t; i < 1024; i += 256) h[i] = 0;
  __syncthreads();
  int base = blockIdx.x * 8192;
  int end = min(base + 8192, E);
  for (int e = base + t; e < end; e += 256)
    atomicAdd(&h[((uint)dst[e]) >> 7], 1);
  __syncthreads();
  for (int i = t; i < 1024; i += 256)
    if (h[i]) atomicAdd(&bcnt[i], h[i]);
}

__global__ __launch_bounds__(1024) void k_bscan(const int* __restrict__ bcnt,
                                                int* __restrict__ bbase,
                                                int* __restrict__ bcur, int P, int E) {
  __shared__ int s[1024];
  int t = threadIdx.x;
  int v = (t < P) ? bcnt[t] : 0;
  s[t] = v;
  __syncthreads();
  for (int off = 1; off < 1024; off <<= 1) {
    int x = (t >= off) ? s[t - off] : 0;
    __syncthreads();
    s[t] += x;
    __syncthreads();
  }
  int ex = s[t] - v;
  if (t < P) {
    bbase[t] = ex;
    bcur[t] = ex;
  }
  if (t == P - 1) bbase[P] = E;
}

__global__ __launch_bounds__(256) void k_bscatter(const int* __restrict__ dst,
                                                  const int* __restrict__ src,
                                                  int* __restrict__ bcur,
                                                  uint* __restrict__ bed, int E) {
  __shared__ int hist[1024];
  __shared__ int exb[1024];
  __shared__ int gpos[1024];
  __shared__ int cur[1024];
  __shared__ int tincl[256];
  __shared__ uint stage[8192];
  __shared__ ushort bof[8192];
  int t = threadIdx.x;
  int base = blockIdx.x * 8192;
  int cnt = min(8192, E - base);
  for (int i = t; i < 1024; i += 256) hist[i] = 0;
  __syncthreads();
  for (int i = t; i < cnt; i += 256)
    atomicAdd(&hist[((uint)dst[base + i]) >> 7], 1);
  __syncthreads();
  // per-thread local scan of 4 consecutive bins + 256-wide scan of sums
  int l0 = hist[4 * t], l1 = hist[4 * t + 1], l2 = hist[4 * t + 2],
      l3 = hist[4 * t + 3];
  int i0 = l0, i1 = i0 + l1, i2 = i1 + l2, tsum = i2 + l3;
  tincl[t] = tsum;
  __syncthreads();
  for (int off = 1; off < 256; off <<= 1) {
    int x = (t >= off) ? tincl[t - off] : 0;
    __syncthreads();
    tincl[t] += x;
    __syncthreads();
  }
  int prior = tincl[t] - tsum;
  exb[4 * t] = prior;          cur[4 * t] = prior;
  exb[4 * t + 1] = prior + i0; cur[4 * t + 1] = prior + i0;
  exb[4 * t + 2] = prior + i1; cur[4 * t + 2] = prior + i1;
  exb[4 * t + 3] = prior + i2; cur[4 * t + 3] = prior + i2;
#pragma unroll
  for (int q = 0; q < 4; q++) {
    int b = 4 * t + q;
    if (hist[b]) gpos[b] = atomicAdd(&bcur[b], hist[b]);
  }
  __syncthreads();
  for (int i = t; i < cnt; i += 256) {
    int d = dst[base + i];
    int b = ((uint)d) >> 7;
    uint val = (((uint)src[base + i]) << 8) | (uint)(d & 127);
    int slot = atomicAdd(&cur[b], 1);
    stage[slot] = val;
    bof[slot] = (ushort)b;
  }
  __syncthreads();
  for (int i = t; i < cnt; i += 256) {
    int b = bof[i];
    bed[gpos[b] + (i - exb[b])] = stage[i];
  }
}

// -------- merged prep: cast h -> {bf16 hb, fp8 h8}; transpose W -> Wt1/Wt2cat
__global__ __launch_bounds__(256) void k_prep(
    const float* __restrict__ in, const float* __restrict__ Ws1,
    const float* __restrict__ Wn1, const float* __restrict__ Ws2,
    const float* __restrict__ Wn2, ushort* __restrict__ outb,
    uchar* __restrict__ out8, ushort* __restrict__ Wt1,
    ushort* __restrict__ Wt2cat, int n8, int CB) {
  if ((int)blockIdx.x < CB) {
    int i = blockIdx.x * 256 + threadIdx.x;
    if (i >= n8) return;
    const float4* p = reinterpret_cast<const float4*>(in) + i * 2;
    float4 a = p[0], b = p[1];
    ushort u[8];
    u[0] = f2bf(a.x); u[1] = f2bf(a.y); u[2] = f2bf(a.z); u[3] = f2bf(a.w);
    u[4] = f2bf(b.x); u[5] = f2bf(b.y); u[6] = f2bf(b.z); u[7] = f2bf(b.w);
    *reinterpret_cast<ulonglong2*>(outb + (size_t)i * 8) =
        *reinterpret_cast<ulonglong2*>(u);
    uint2 q;
    int w0 = __builtin_amdgcn_cvt_pk_fp8_f32(a.x, a.y, 0, false);
    w0 = __builtin_amdgcn_cvt_pk_fp8_f32(a.z, a.w, w0, true);
    int w1 = __builtin_amdgcn_cvt_pk_fp8_f32(b.x, b.y, 0, false);
    w1 = __builtin_amdgcn_cvt_pk_fp8_f32(b.z, b.w, w1, true);
    q.x = (uint)w0;
    q.y = (uint)w1;
    *reinterpret_cast<uint2*>(out8 + (size_t)i * 8) = q;
  } else {
    int idx = ((int)blockIdx.x - CB) * 256 + threadIdx.x;
    if (idx < 128 * 256) {
      int n = idx >> 8, k = idx & 255;
      float v = (k < 128) ? Ws1[(size_t)k * 128 + n]
                          : Wn1[(size_t)(k - 128) * 128 + n];
      Wt1[idx] = f2bf(v);
    } else if (idx < 128 * 256 + 128 * 128) {
      int j = idx - 128 * 256;
      int n = j >> 7, k = j & 127;
      float v = (n < 64) ? Wn2[(size_t)k * 64 + n] : Ws2[(size_t)k * 64 + (n - 64)];
      Wt2cat[j] = f2bf(v);
    }
  }
}

#define UNPACK16(v, f)                                                         \
  do {                                                                         \
    f32x2 p_;                                                                  \
    p_ = __builtin_amdgcn_cvt_pk_f32_fp8((int)(v).x, false); f[0] = p_.x; f[1] = p_.y;  \
    p_ = __builtin_amdgcn_cvt_pk_f32_fp8((int)(v).x, true);  f[2] = p_.x; f[3] = p_.y;  \
    p_ = __builtin_amdgcn_cvt_pk_f32_fp8((int)(v).y, false); f[4] = p_.x; f[5] = p_.y;  \
    p_ = __builtin_amdgcn_cvt_pk_f32_fp8((int)(v).y, true);  f[6] = p_.x; f[7] = p_.y;  \
    p_ = __builtin_amdgcn_cvt_pk_f32_fp8((int)(v).z, false); f[8] = p_.x; f[9] = p_.y;  \
    p_ = __builtin_amdgcn_cvt_pk_f32_fp8((int)(v).z, true);  f[10] = p_.x; f[11] = p_.y;\
    p_ = __builtin_amdgcn_cvt_pk_f32_fp8((int)(v).w, false); f[12] = p_.x; f[13] = p_.y;\
    p_ = __builtin_amdgcn_cvt_pk_f32_fp8((int)(v).w, true);  f[14] = p_.x; f[15] = p_.y;\
  } while (0)

// -------- layer-1 bucket-major aggregate: fp8 128B rows -> aggb bf16 --------
// one block per 128-node bucket; acc in LDS (row stride 129 f32: conflict-free
// columns); 8-lane groups stream edges; bank-rotated ds_add_f32.
__global__ __launch_bounds__(512) void k_agg1b(const uchar* __restrict__ X8,
                                               const uint* __restrict__ bed,
                                               const int* __restrict__ bbase,
                                               ushort* __restrict__ outb, int N) {
  __shared__ float acc[128 * 129];  // 66 KB
  __shared__ int dcnt[128];
  int t = threadIdx.x;
  int b = blockIdx.x;
  for (int i = t; i < 128 * 129 / 4; i += 512)
    *reinterpret_cast<float4*>(acc + i * 4) = make_float4(0.f, 0.f, 0.f, 0.f);
  acc[128 * 129 - 1] = 0.f;  // tail (16512 = 4128*4 exactly; keep safe)
  if (t < 128) dcnt[t] = 0;
  __syncthreads();
  int e0 = bbase[b], e1 = bbase[b + 1];
  for (int e = e0 + t; e < e1; e += 512) atomicAdd(&dcnt[bed[e] & 127u], 1);
  int g = t >> 3, sl = t & 7;
  for (int e = e0 + g; e < e1; e += 64) {
    uint pk = bed[e];
    int n = pk & 127;
    int src = (int)(pk >> 8);
    uint4 v = *reinterpret_cast<const uint4*>(X8 + (size_t)src * 128 + sl * 16);
    float f[16];
    UNPACK16(v, f);
    float* row = acc + n * 129 + sl * 16;
#pragma unroll
    for (int k = 0; k < 16; k++) {
      int kk = (k + 2 * sl) & 15;  // spread 8 lanes across 8 banks
      atomicAdd(row + kk, f[kk]);
    }
  }
  __syncthreads();
  int nodeL = t >> 2, q = t & 3;
  int nodeG = (b << 7) + nodeL;
  if (nodeG < N) {
    float rinv = 1.0f / fmaxf((float)dcnt[nodeL], 1.0f);
    ushort o[32];
#pragma unroll
    for (int k = 0; k < 32; k++)
      o[k] = f2bf(acc[nodeL * 129 + q * 32 + k] * rinv);
    ulonglong2* dst =
        reinterpret_cast<ulonglong2*>(outb + (size_t)nodeG * 128 + q * 32);
#pragma unroll
    for (int k = 0; k < 4; k++) dst[k] = reinterpret_cast<ulonglong2*>(o)[k];
  }
}

// -------- layer-2 bucket-major gather+add: fp8 64B rows -> out f32 ---------
__global__ __launch_bounds__(512) void k_agg_outb(const uchar* __restrict__ P8,
                                                  const float* __restrict__ S,
                                                  const uint* __restrict__ bed,
                                                  const int* __restrict__ bbase,
                                                  float* __restrict__ out, int N) {
  __shared__ float acc[128 * 65];  // 33.3 KB
  __shared__ int dcnt[128];
  int t = threadIdx.x;
  int b = blockIdx.x;
  for (int i = t; i < 128 * 65 / 4; i += 512)
    *reinterpret_cast<float4*>(acc + i * 4) = make_float4(0.f, 0.f, 0.f, 0.f);
  if (t < 128) dcnt[t] = 0;
  __syncthreads();
  int e0 = bbase[b], e1 = bbase[b + 1];
  for (int e = e0 + t; e < e1; e += 512) atomicAdd(&dcnt[bed[e] & 127u], 1);
  int g = t >> 2, sl = t & 3;
  for (int e = e0 + g; e < e1; e += 128) {
    uint pk = bed[e];
    int n = pk & 127;
    int src = (int)(pk >> 8);
    uint4 v = *reinterpret_cast<const uint4*>(P8 + (size_t)src * 64 + sl * 16);
    float f[16];
    UNPACK16(v, f);
    float* row = acc + n * 65 + sl * 16;
#pragma unroll
    for (int k = 0; k < 16; k++) {
      int kk = (k + 4 * sl) & 15;
      atomicAdd(row + kk, f[kk]);
    }
  }
  __syncthreads();
  int nodeL = t >> 2, q = t & 3;
  int nodeG = (b << 7) + nodeL;
  if (nodeG < N) {
    float rinv = 1.0f / fmaxf((float)dcnt[nodeL], 1.0f);
    const float4* sp =
        reinterpret_cast<const float4*>(S + (size_t)nodeG * 64 + q * 16);
    float4* op = reinterpret_cast<float4*>(out + (size_t)nodeG * 64 + q * 16);
#pragma unroll
    for (int w = 0; w < 4; w++) {
      float4 s = sp[w];
      float4 o;
      o.x = fmaxf(acc[nodeL * 65 + q * 16 + w * 4 + 0] * rinv + s.x, 0.f);
      o.y = fmaxf(acc[nodeL * 65 + q * 16 + w * 4 + 1] * rinv + s.y, 0.f);
      o.z = fmaxf(acc[nodeL * 65 + q * 16 + w * 4 + 2] * rinv + s.z, 0.f);
      o.w = fmaxf(acc[nodeL * 65 + q * 16 + w * 4 + 3] * rinv + s.w, 0.f);
      op[w] = o;
    }
  }
}

// ---------------- PERSISTENT fused GEMM (v1, R11/R15-proven) ----------------
__global__ __launch_bounds__(512) void k_persist(const ushort* __restrict__ Xb,
                                                 const ushort* __restrict__ Gb,
                                                 const ushort* __restrict__ Wt1,
                                                 const ushort* __restrict__ Wt2,
                                                 const float* __restrict__ b1,
                                                 const float* __restrict__ b2,
                                                 uchar* __restrict__ P8,
                                                 float* __restrict__ S2,
                                                 int M, int ntiles) {
  __shared__ ushort W1s[128 * 256];  // 64 KB
  __shared__ ushort W2s[128 * 128];  // 32 KB
  __shared__ char Xs[64 * 256 * 2];  // 32 KB X tile; h1 reuses [0,16KB)

  const int t = threadIdx.x;
  const int lane = t & 63;
  const int w = t >> 6;
  const int wm = w >> 2, wn = w & 3;

#pragma unroll
  for (int i = 0; i < 8; i++) {
    int g = t + 512 * i;
    int row = g >> 5, kph = g & 31;
    const ushort* src = Wt1 + (size_t)row * 256 + ((kph ^ (row & 7)) << 3);
    char* dst = (char*)W1s + ((g & ~63) << 4);
    GLDS(src, dst);
  }
#pragma unroll
  for (int i = 0; i < 4; i++) {
    int g = t + 512 * i;
    int row = g >> 4, kph = g & 15;
    const ushort* src = Wt2 + (size_t)row * 128 + ((kph ^ (row & 7)) << 3);
    char* dst = (char*)W2s + ((g & ~63) << 4);
    GLDS(src, dst);
  }

  float bb1[2], bb2[2];
#pragma unroll
  for (int fn = 0; fn < 2; fn++) {
    int colg = wn * 32 + fn * 16 + (lane & 15);
    bb1[fn] = b1[colg];
    bb2[fn] = (colg >= 64) ? b2[colg - 64] : 0.f;
  }

  int tile = blockIdx.x;
  if (tile >= ntiles) return;

  uint4 xr0, xr1, xr2, xr3;
#define LOADX(tl)                                                              \
  {                                                                            \
    int g, row, kk, gm;                                                        \
    const ushort* s;                                                           \
    g = t;            row = g >> 5; kk = (g & 31) ^ (row & 7);                 \
    gm = min((tl) * 64 + row, M - 1);                                          \
    s = (kk < 16) ? Xb + (size_t)gm * 128 + kk * 8                             \
                  : Gb + (size_t)gm * 128 + (kk - 16) * 8;                     \
    xr0 = *reinterpret_cast<const uint4*>(s);                                  \
    g = t + 512;      row = g >> 5; kk = (g & 31) ^ (row & 7);                 \
    gm = min((tl) * 64 + row, M - 1);                                          \
    s = (kk < 16) ? Xb + (size_t)gm * 128 + kk * 8                             \
                  : Gb + (size_t)gm * 128 + (kk - 16) * 8;                     \
    xr1 = *reinterpret_cast<const uint4*>(s);                                  \
    g = t + 1024;     row = g >> 5; kk = (g & 31) ^ (row & 7);                 \
    gm = min((tl) * 64 + row, M - 1);                                          \
    s = (kk < 16) ? Xb + (size_t)gm * 128 + kk * 8                             \
                  : Gb + (size_t)gm * 128 + (kk - 16) * 8;                     \
    xr2 = *reinterpret_cast<const uint4*>(s);                                  \
    g = t + 1536;     row = g >> 5; kk = (g & 31) ^ (row & 7);                 \
    gm = min((tl) * 64 + row, M - 1);                                          \
    s = (kk < 16) ? Xb + (size_t)gm * 128 + kk * 8                             \
                  : Gb + (size_t)gm * 128 + (kk - 16) * 8;                     \
    xr3 = *reinterpret_cast<const uint4*>(s);                                  \
  }
#define WRITEX()                                                               \
  {                                                                            \
    *reinterpret_cast<uint4*>(Xs + (size_t)t * 16) = xr0;                      \
    *reinterpret_cast<uint4*>(Xs + (size_t)(t + 512) * 16) = xr1;              \
    *reinterpret_cast<uint4*>(Xs + (size_t)(t + 1024) * 16) = xr2;             \
    *reinterpret_cast<uint4*>(Xs + (size_t)(t + 1536) * 16) = xr3;             \
  }

  LOADX(tile);
  WRITEX();
  __syncthreads();

  while (true) {
    int next = tile + gridDim.x;
    bool more = (next < ntiles);
    if (more) LOADX(next);

    f32x4 acc[2][2] = {};
#pragma unroll
    for (int ks = 0; ks < 8; ks++) {
      int ga = ks * 4 + (lane >> 4);
      short8 af[2], bf[2];
#pragma unroll
      for (int fm = 0; fm < 2; fm++) {
        int row = wm * 32 + fm * 16 + (lane & 15);
        af[fm] = *reinterpret_cast<const short8*>(
            Xs + row * 512 + ((ga ^ (row & 7)) << 4));
      }
#pragma unroll
      for (int fn = 0; fn < 2; fn++) {
        int colr = wn * 32 + fn * 16 + (lane & 15);
        bf[fn] = *reinterpret_cast<const short8*>(
            (char*)W1s + colr * 512 + ((ga ^ (colr & 7)) << 4));
      }
#pragma unroll
      for (int fm = 0; fm < 2; fm++)
#pragma unroll
        for (int fn = 0; fn < 2; fn++)
          acc[fm][fn] = __builtin_amdgcn_mfma_f32_16x16x32_bf16(
              af[fm], bf[fn], acc[fm][fn], 0, 0, 0);
    }

    __builtin_amdgcn_s_barrier();
    FENCE();

#pragma unroll
    for (int fn = 0; fn < 2; fn++) {
      int colg = wn * 32 + fn * 16 + (lane & 15);
      int gg = colg >> 3, cb = (colg & 7) * 2;
#pragma unroll
      for (int fm = 0; fm < 2; fm++) {
#pragma unroll
        for (int r = 0; r < 4; r++) {
          int rowl = wm * 32 + fm * 16 + (lane >> 4) * 4 + r;
          ushort hv = f2bf(fmaxf(acc[fm][fn][r] + bb1[fn], 0.f));
          *reinterpret_cast<ushort*>(
              Xs + rowl * 256 + ((gg ^ (rowl & 7)) << 4) + cb) = hv;
        }
      }
    }
    LGKM0();
    __builtin_amdgcn_s_barrier();
    FENCE();

    f32x4 acc2[2][2] = {};
#pragma unroll
    for (int ks = 0; ks < 4; ks++) {
      int gk = ks * 4 + (lane >> 4);
      short8 af[2], bf[2];
#pragma unroll
      for (int fm = 0; fm < 2; fm++) {
        int row = wm * 32 + fm * 16 + (lane & 15);
        af[fm] = *reinterpret_cast<const short8*>(
            Xs + row * 256 + ((gk ^ (row & 7)) << 4));
      }
#pragma unroll
      for (int fn = 0; fn < 2; fn++) {
        int colr = wn * 32 + fn * 16 + (lane & 15);
        bf[fn] = *reinterpret_cast<const short8*>(
            (char*)W2s + colr * 256 + ((gk ^ (colr & 7)) << 4));
      }
#pragma unroll
      for (int fm = 0; fm < 2; fm++)
#pragma unroll
        for (int fn = 0; fn < 2; fn++)
          acc2[fm][fn] = __builtin_amdgcn_mfma_f32_16x16x32_bf16(
              af[fm], bf[fn], acc2[fm][fn], 0, 0, 0);
    }

#pragma unroll
    for (int fn = 0; fn < 2; fn++) {
      int colg = wn * 32 + fn * 16 + (lane & 15);
#pragma unroll
      for (int fm = 0; fm < 2; fm++) {
#pragma unroll
        for (int r = 0; r < 4; r++) {
          int rowg = tile * 64 + wm * 32 + fm * 16 + (lane >> 4) * 4 + r;
          if (rowg >= M) continue;
          if (colg < 64) {
            float v = acc2[fm][fn][r];
            int b8 = __builtin_amdgcn_cvt_pk_fp8_f32(v, v, 0, false);
            P8[(size_t)rowg * 64 + colg] = (uchar)(b8 & 0xff);
          } else {
            S2[(size_t)rowg * 64 + (colg - 64)] = acc2[fm][fn][r] + bb2[fn];
          }
        }
      }
    }

    if (!more) break;
    __builtin_amdgcn_s_barrier();
    FENCE();
    WRITEX();
    LGKM0();
    __builtin_amdgcn_s_barrier();
    FENCE();
    tile = next;
  }
#undef LOADX
#undef WRITEX
}

extern "C" void kernel_launch(void* const* d_in, const int* in_sizes, int n_in,
                              void* d_out, int out_size, void* d_ws, size_t ws_size,
                              hipStream_t stream) {
  const float* h = (const float*)d_in[0];
  const int* esrc = (const int*)d_in[1];
  const int* edst = (const int*)d_in[2];
  const float* Ws1 = (const float*)d_in[3];
  const float* Wn1 = (const float*)d_in[4];
  const float* b1 = (const float*)d_in[5];
  const float* Ws2 = (const float*)d_in[6];
  const float* Wn2 = (const float*)d_in[7];
  const float* b2 = (const float*)d_in[8];
  float* out = (float*)d_out;

  const int N = in_sizes[0] / 128;  // 100000
  const int E = in_sizes[1];        // 1600000
  const int P = (N + 127) >> 7;     // 782 buckets of 128 nodes

  char* base = (char*)d_ws;
  size_t off = 0;
  auto alloc = [&](size_t bytes) {
    size_t o = off;
    off += (bytes + 255) & ~(size_t)255;
    return o;
  };
  int* bcnt = (int*)(base + alloc(1025 * 4));
  int* bbase = (int*)(base + alloc(1025 * 4));
  int* bcur = (int*)(base + alloc(1025 * 4));
  uint* bed = (uint*)(base + alloc((size_t)E * 4));
  ushort* hb = (ushort*)(base + alloc((size_t)N * 128 * 2));
  uchar* h8 = (uchar*)(base + alloc((size_t)N * 128));
  ushort* aggb = (ushort*)(base + alloc((size_t)N * 128 * 2));
  uchar* p8 = (uchar*)(base + alloc((size_t)N * 64));
  ushort* Wt1 = (ushort*)(base + alloc(128 * 256 * 2));
  ushort* Wt2cat = (ushort*)(base + alloc(128 * 128 * 2));
  // overlay: s2f->aggb (persist reads tile rows of aggb before writing them)
  float* s2f = (float*)aggb;

  const int NCH = (E + 8191) / 8192;
  const int NT = (N + 63) / 64;  // 1563 M-tiles
  const int n8 = N * 128 / 8;
  const int CB = (n8 + 255) / 256;
  const int WB = (128 * 256 + 128 * 128) / 256;

  (void)hipMemsetAsync(bcnt, 0, 1025 * 4, stream);
  k_bhist<<<NCH, 256, 0, stream>>>(edst, bcnt, E);
  k_bscan<<<1, 1024, 0, stream>>>(bcnt, bbase, bcur, P, E);
  k_bscatter<<<NCH, 256, 0, stream>>>(edst, esrc, bcur, bed, E);

  k_prep<<<CB + WB, 256, 0, stream>>>(h, Ws1, Wn1, Ws2, Wn2, hb, h8, Wt1,
                                      Wt2cat, n8, CB);

  k_agg1b<<<P, 512, 0, stream>>>(h8, bed, bbase, aggb, N);
  k_persist<<<256, 512, 0, stream>>>(hb, aggb, Wt1, Wt2cat, b1, b2, p8, s2f, N, NT);
  k_agg_outb<<<P, 512, 0, stream>>>(p8, s2f, bed, bbase, out, N);
}

// Round 17
// 165.527 us; speedup vs baseline: 12.7204x; 12.7204x over previous
//
#include <hip/hip_runtime.h>

// GraphSAGE 2-layer (mean agg), N=100K, E=1.6M, 128->128->64, f32 in/out.
// R17 = exact revert to R15 (best measured: 165.2us).
// R16 post-mortem: bucket-major LDS-atomic aggregation serialized (204.8M
// scalar ds_add_f32 ops -> k_agg1b 1352us, HBM 1%). Register-gather wins.
// Config: bucketed-CSR build + fp8 gather (8-lane groups, 8 loads in flight)
// + persistent fused GEMM v1 (W in LDS staged once, grid-stride M-tiles,
// reg-prefetch pipeline, raw barriers) + fused layer-2 gather+add+relu.
// Overlays: p8->bed (dead after CSR), s2f->aggb (tile-local rows, WAR-safe).

typedef __attribute__((ext_vector_type(8))) short short8;
typedef __attribute__((ext_vector_type(4))) float f32x4;
typedef __attribute__((ext_vector_type(2))) float f32x2;

__device__ __forceinline__ ushort f2bf(float f) {
  uint u = __float_as_uint(f);
  u += 0x7fffu + ((u >> 16) & 1u);  // round-to-nearest-even
  return (ushort)(u >> 16);
}

#define GLDS(src, dst)                                                        \
  __builtin_amdgcn_global_load_lds(                                           \
      (const __attribute__((address_space(1))) void*)(src),                   \
      (__attribute__((address_space(3))) void*)(dst), 16, 0, 0)

#define FENCE() asm volatile("" ::: "memory")
#define LGKM0() asm volatile("s_waitcnt lgkmcnt(0)" ::: "memory")

// ================= bucketed CSR build =================
__global__ __launch_bounds__(256) void k_bhist(const int* __restrict__ dst,
                                               int* __restrict__ bcnt, int E) {
  __shared__ int h[512];
  int t = threadIdx.x;
  for (int i = t; i < 512; i += 256) h[i] = 0;
  __syncthreads();
  int base = blockIdx.x * 8192;
  int end = min(base + 8192, E);
  for (int e = base + t; e < end; e += 256)
    atomicAdd(&h[((uint)dst[e]) >> 8], 1);
  __syncthreads();
  for (int i = t; i < 512; i += 256)
    if (h[i]) atomicAdd(&bcnt[i], h[i]);
}

__global__ __launch_bounds__(512) void k_bscan(const int* __restrict__ bcnt,
                                               int* __restrict__ bbase,
                                               int* __restrict__ bcur, int P, int E) {
  __shared__ int s[512];
  int t = threadIdx.x;
  int v = (t < P) ? bcnt[t] : 0;
  s[t] = v;
  __syncthreads();
  for (int off = 1; off < 512; off <<= 1) {
    int x = (t >= off) ? s[t - off] : 0;
    __syncthreads();
    s[t] += x;
    __syncthreads();
  }
  int ex = s[t] - v;
  if (t < P) {
    bbase[t] = ex;
    bcur[t] = ex;
  }
  if (t == P - 1) bbase[P] = E;
}

__global__ __launch_bounds__(256) void k_bscatter(const int* __restrict__ dst,
                                                  const int* __restrict__ src,
                                                  int* __restrict__ bcur,
                                                  uint* __restrict__ bed, int E, int P) {
  __shared__ int hist[512];
  __shared__ int incl[512];
  __shared__ int gpos[512];
  __shared__ int cur[512];
  __shared__ uint stage[8192];
  __shared__ ushort bof[8192];
  int t = threadIdx.x;
  int base = blockIdx.x * 8192;
  int cnt = min(8192, E - base);
  for (int i = t; i < 512; i += 256) hist[i] = 0;
  __syncthreads();
  for (int i = t; i < cnt; i += 256)
    atomicAdd(&hist[((uint)dst[base + i]) >> 8], 1);
  __syncthreads();
  incl[t] = hist[t];
  incl[t + 256] = hist[t + 256];
  __syncthreads();
  for (int off = 1; off < 512; off <<= 1) {
    int i0 = t, i1 = t + 256;
    int a0 = (i0 >= off) ? incl[i0 - off] : 0;
    int a1 = (i1 >= off) ? incl[i1 - off] : 0;
    __syncthreads();
    incl[i0] += a0;
    incl[i1] += a1;
    __syncthreads();
  }
  cur[t] = incl[t] - hist[t];
  cur[t + 256] = incl[t + 256] - hist[t + 256];
  for (int i = t; i < P; i += 256)
    if (hist[i]) gpos[i] = atomicAdd(&bcur[i], hist[i]);
  __syncthreads();
  for (int i = t; i < cnt; i += 256) {
    int d = dst[base + i];
    int b = ((uint)d) >> 8;
    uint val = (((uint)src[base + i]) << 8) | (uint)(d & 255);
    int slot = atomicAdd(&cur[b], 1);
    stage[slot] = val;
    bof[slot] = (ushort)b;
  }
  __syncthreads();
  for (int i = t; i < cnt; i += 256) {
    int b = bof[i];
    int ex = incl[b] - hist[b];
    bed[gpos[b] + (i - ex)] = stage[i];
  }
}

__global__ __launch_bounds__(256) void k_bcsr(const uint* __restrict__ bed,
                                              const int* __restrict__ bbase,
                                              int* __restrict__ deg,
                                              int* __restrict__ rs,
                                              int* __restrict__ col, int N) {
  __shared__ int dcnt[256];
  __shared__ int sofs[256];
  int b = blockIdx.x, t = threadIdx.x;
  int e0 = bbase[b], e1 = bbase[b + 1];
  dcnt[t] = 0;
  __syncthreads();
  for (int e = e0 + t; e < e1; e += 256) atomicAdd(&dcnt[bed[e] & 255u], 1);
  __syncthreads();
  int v0 = dcnt[t];
  sofs[t] = v0;
  __syncthreads();
  for (int off = 1; off < 256; off <<= 1) {
    int x = (t >= off) ? sofs[t - off] : 0;
    __syncthreads();
    sofs[t] += x;
    __syncthreads();
  }
  int ex = sofs[t] - v0;
  int node = (b << 8) + t;
  if (node < N) {
    deg[node] = v0;
    rs[node] = e0 + ex;
  }
  __syncthreads();
  dcnt[t] = e0 + ex;
  __syncthreads();
  for (int e = e0 + t; e < e1; e += 256) {
    uint v = bed[e];
    int pos = atomicAdd(&dcnt[v & 255u], 1);
    col[pos] = (int)(v >> 8);
  }
}

// -------- merged prep: cast h -> {bf16 hb, fp8 h8}; transpose W -> Wt1/Wt2cat
__global__ __launch_bounds__(256) void k_prep(
    const float* __restrict__ in, const float* __restrict__ Ws1,
    const float* __restrict__ Wn1, const float* __restrict__ Ws2,
    const float* __restrict__ Wn2, ushort* __restrict__ outb,
    uchar* __restrict__ out8, ushort* __restrict__ Wt1,
    ushort* __restrict__ Wt2cat, int n8, int CB) {
  if ((int)blockIdx.x < CB) {
    int i = blockIdx.x * 256 + threadIdx.x;
    if (i >= n8) return;
    const float4* p = reinterpret_cast<const float4*>(in) + i * 2;
    float4 a = p[0], b = p[1];
    ushort u[8];
    u[0] = f2bf(a.x); u[1] = f2bf(a.y); u[2] = f2bf(a.z); u[3] = f2bf(a.w);
    u[4] = f2bf(b.x); u[5] = f2bf(b.y); u[6] = f2bf(b.z); u[7] = f2bf(b.w);
    *reinterpret_cast<ulonglong2*>(outb + (size_t)i * 8) =
        *reinterpret_cast<ulonglong2*>(u);
    uint2 q;
    int w0 = __builtin_amdgcn_cvt_pk_fp8_f32(a.x, a.y, 0, false);
    w0 = __builtin_amdgcn_cvt_pk_fp8_f32(a.z, a.w, w0, true);
    int w1 = __builtin_amdgcn_cvt_pk_fp8_f32(b.x, b.y, 0, false);
    w1 = __builtin_amdgcn_cvt_pk_fp8_f32(b.z, b.w, w1, true);
    q.x = (uint)w0;
    q.y = (uint)w1;
    *reinterpret_cast<uint2*>(out8 + (size_t)i * 8) = q;
  } else {
    int idx = ((int)blockIdx.x - CB) * 256 + threadIdx.x;
    if (idx < 128 * 256) {
      int n = idx >> 8, k = idx & 255;
      float v = (k < 128) ? Ws1[(size_t)k * 128 + n]
                          : Wn1[(size_t)(k - 128) * 128 + n];
      Wt1[idx] = f2bf(v);
    } else if (idx < 128 * 256 + 128 * 128) {
      int j = idx - 128 * 256;
      int n = j >> 7, k = j & 127;
      float v = (n < 64) ? Wn2[(size_t)k * 64 + n] : Ws2[(size_t)k * 64 + (n - 64)];
      Wt2cat[j] = f2bf(v);
    }
  }
}

#define ACC16(v)                                                               \
  do {                                                                         \
    f32x2 f;                                                                   \
    f = __builtin_amdgcn_cvt_pk_f32_fp8((int)(v).x, false); a[0] += f.x; a[1] += f.y;  \
    f = __builtin_amdgcn_cvt_pk_f32_fp8((int)(v).x, true);  a[2] += f.x; a[3] += f.y;  \
    f = __builtin_amdgcn_cvt_pk_f32_fp8((int)(v).y, false); a[4] += f.x; a[5] += f.y;  \
    f = __builtin_amdgcn_cvt_pk_f32_fp8((int)(v).y, true);  a[6] += f.x; a[7] += f.y;  \
    f = __builtin_amdgcn_cvt_pk_f32_fp8((int)(v).z, false); a[8] += f.x; a[9] += f.y;  \
    f = __builtin_amdgcn_cvt_pk_f32_fp8((int)(v).z, true);  a[10] += f.x; a[11] += f.y;\
    f = __builtin_amdgcn_cvt_pk_f32_fp8((int)(v).w, false); a[12] += f.x; a[13] += f.y;\
    f = __builtin_amdgcn_cvt_pk_f32_fp8((int)(v).w, true);  a[14] += f.x; a[15] += f.y;\
  } while (0)

// -------- layer-1 aggregate: fp8 128B rows; 8-lane group per node ---------
// Chunk of 8 neighbors: issue ALL 8 row loads (dwordx4, independent), then
// convert. Guards are group-uniform (cnt identical across group); shfls
// executed unconditionally by the whole group (sources always active).
__global__ __launch_bounds__(256) void k_agg1(const uchar* __restrict__ X8,
                                              const int* __restrict__ col,
                                              const int* __restrict__ rs,
                                              const int* __restrict__ deg,
                                              ushort* __restrict__ outb, int n) {
  int node = blockIdx.x * 32 + (threadIdx.x >> 3);
  if (node >= n) return;
  int sl = threadIdx.x & 7;
  int gbase = (threadIdx.x & 63) & ~7;
  int r0 = rs[node], d = deg[node];
  float a[16] = {};
  int j = 0;
  while (j < d) {
    int cnt = min(d - j, 8);
    int myc = (sl < cnt) ? col[r0 + j + sl] : 0;
    int c0 = __shfl(myc, gbase + 0, 64);
    int c1 = __shfl(myc, gbase + 1, 64);
    int c2 = __shfl(myc, gbase + 2, 64);
    int c3 = __shfl(myc, gbase + 3, 64);
    int c4 = __shfl(myc, gbase + 4, 64);
    int c5 = __shfl(myc, gbase + 5, 64);
    int c6 = __shfl(myc, gbase + 6, 64);
    int c7 = __shfl(myc, gbase + 7, 64);
    uint4 v0, v1, v2, v3, v4, v5, v6, v7;
    // all loads issued before any conversion -> 8 in flight per lane
    if (cnt > 0) v0 = *reinterpret_cast<const uint4*>(X8 + (size_t)c0 * 128 + sl * 16);
    if (cnt > 1) v1 = *reinterpret_cast<const uint4*>(X8 + (size_t)c1 * 128 + sl * 16);
    if (cnt > 2) v2 = *reinterpret_cast<const uint4*>(X8 + (size_t)c2 * 128 + sl * 16);
    if (cnt > 3) v3 = *reinterpret_cast<const uint4*>(X8 + (size_t)c3 * 128 + sl * 16);
    if (cnt > 4) v4 = *reinterpret_cast<const uint4*>(X8 + (size_t)c4 * 128 + sl * 16);
    if (cnt > 5) v5 = *reinterpret_cast<const uint4*>(X8 + (size_t)c5 * 128 + sl * 16);
    if (cnt > 6) v6 = *reinterpret_cast<const uint4*>(X8 + (size_t)c6 * 128 + sl * 16);
    if (cnt > 7) v7 = *reinterpret_cast<const uint4*>(X8 + (size_t)c7 * 128 + sl * 16);
    if (cnt > 0) ACC16(v0);
    if (cnt > 1) ACC16(v1);
    if (cnt > 2) ACC16(v2);
    if (cnt > 3) ACC16(v3);
    if (cnt > 4) ACC16(v4);
    if (cnt > 5) ACC16(v5);
    if (cnt > 6) ACC16(v6);
    if (cnt > 7) ACC16(v7);
    j += cnt;
  }
  float rinv = 1.0f / fmaxf((float)d, 1.0f);
  ushort o[16];
#pragma unroll
  for (int k = 0; k < 16; k++) o[k] = f2bf(a[k] * rinv);
  ulonglong2* dst = reinterpret_cast<ulonglong2*>(outb + (size_t)node * 128 + sl * 16);
  dst[0] = reinterpret_cast<ulonglong2*>(o)[0];
  dst[1] = reinterpret_cast<ulonglong2*>(o)[1];
}

// -------- layer-2 fused gather+add: fp8 64B rows; 4-lane group per node ----
// Chunk of 8 (two index regs), all 8 loads in flight before converting.
__global__ __launch_bounds__(256) void k_agg_out(const uchar* __restrict__ P8,
                                                 const float* __restrict__ S,
                                                 const int* __restrict__ col,
                                                 const int* __restrict__ rs,
                                                 const int* __restrict__ deg,
                                                 float* __restrict__ out, int n) {
  int node = blockIdx.x * 64 + (threadIdx.x >> 2);
  if (node >= n) return;
  int sl = threadIdx.x & 3;
  int gbase = (threadIdx.x & 63) & ~3;
  int r0 = rs[node], d = deg[node];
  float a[16] = {};
  int j = 0;
  while (j < d) {
    int cnt = min(d - j, 8);
    int myc0 = (sl < cnt) ? col[r0 + j + sl] : 0;
    int myc1 = (sl + 4 < cnt) ? col[r0 + j + 4 + sl] : 0;
    int c0 = __shfl(myc0, gbase + 0, 64);
    int c1 = __shfl(myc0, gbase + 1, 64);
    int c2 = __shfl(myc0, gbase + 2, 64);
    int c3 = __shfl(myc0, gbase + 3, 64);
    int c4 = __shfl(myc1, gbase + 0, 64);
    int c5 = __shfl(myc1, gbase + 1, 64);
    int c6 = __shfl(myc1, gbase + 2, 64);
    int c7 = __shfl(myc1, gbase + 3, 64);
    uint4 v0, v1, v2, v3, v4, v5, v6, v7;
    if (cnt > 0) v0 = *reinterpret_cast<const uint4*>(P8 + (size_t)c0 * 64 + sl * 16);
    if (cnt > 1) v1 = *reinterpret_cast<const uint4*>(P8 + (size_t)c1 * 64 + sl * 16);
    if (cnt > 2) v2 = *reinterpret_cast<const uint4*>(P8 + (size_t)c2 * 64 + sl * 16);
    if (cnt > 3) v3 = *reinterpret_cast<const uint4*>(P8 + (size_t)c3 * 64 + sl * 16);
    if (cnt > 4) v4 = *reinterpret_cast<const uint4*>(P8 + (size_t)c4 * 64 + sl * 16);
    if (cnt > 5) v5 = *reinterpret_cast<const uint4*>(P8 + (size_t)c5 * 64 + sl * 16);
    if (cnt > 6) v6 = *reinterpret_cast<const uint4*>(P8 + (size_t)c6 * 64 + sl * 16);
    if (cnt > 7) v7 = *reinterpret_cast<const uint4*>(P8 + (size_t)c7 * 64 + sl * 16);
    if (cnt > 0) ACC16(v0);
    if (cnt > 1) ACC16(v1);
    if (cnt > 2) ACC16(v2);
    if (cnt > 3) ACC16(v3);
    if (cnt > 4) ACC16(v4);
    if (cnt > 5) ACC16(v5);
    if (cnt > 6) ACC16(v6);
    if (cnt > 7) ACC16(v7);
    j += cnt;
  }
  float rinv = 1.0f / fmaxf((float)d, 1.0f);
  const float4* sp = reinterpret_cast<const float4*>(S + (size_t)node * 64 + sl * 16);
  float4* op = reinterpret_cast<float4*>(out + (size_t)node * 64 + sl * 16);
#pragma unroll
  for (int q = 0; q < 4; q++) {
    float4 s = sp[q];
    float4 o;
    o.x = fmaxf(a[q * 4 + 0] * rinv + s.x, 0.f);
    o.y = fmaxf(a[q * 4 + 1] * rinv + s.y, 0.f);
    o.z = fmaxf(a[q * 4 + 2] * rinv + s.z, 0.f);
    o.w = fmaxf(a[q * 4 + 3] * rinv + s.w, 0.f);
    op[q] = o;
  }
}

// ---------------- PERSISTENT fused GEMM (v1, R11-proven) ----------------
__global__ __launch_bounds__(512) void k_persist(const ushort* __restrict__ Xb,
                                                 const ushort* __restrict__ Gb,
                                                 const ushort* __restrict__ Wt1,
                                                 const ushort* __restrict__ Wt2,
                                                 const float* __restrict__ b1,
                                                 const float* __restrict__ b2,
                                                 uchar* __restrict__ P8,
                                                 float* __restrict__ S2,
                                                 int M, int ntiles) {
  __shared__ ushort W1s[128 * 256];  // 64 KB
  __shared__ ushort W2s[128 * 128];  // 32 KB
  __shared__ char Xs[64 * 256 * 2];  // 32 KB X tile; h1 reuses [0,16KB)

  const int t = threadIdx.x;
  const int lane = t & 63;
  const int w = t >> 6;
  const int wm = w >> 2, wn = w & 3;

#pragma unroll
  for (int i = 0; i < 8; i++) {
    int g = t + 512 * i;
    int row = g >> 5, kph = g & 31;
    const ushort* src = Wt1 + (size_t)row * 256 + ((kph ^ (row & 7)) << 3);
    char* dst = (char*)W1s + ((g & ~63) << 4);
    GLDS(src, dst);
  }
#pragma unroll
  for (int i = 0; i < 4; i++) {
    int g = t + 512 * i;
    int row = g >> 4, kph = g & 15;
    const ushort* src = Wt2 + (size_t)row * 128 + ((kph ^ (row & 7)) << 3);
    char* dst = (char*)W2s + ((g & ~63) << 4);
    GLDS(src, dst);
  }

  float bb1[2], bb2[2];
#pragma unroll
  for (int fn = 0; fn < 2; fn++) {
    int colg = wn * 32 + fn * 16 + (lane & 15);
    bb1[fn] = b1[colg];
    bb2[fn] = (colg >= 64) ? b2[colg - 64] : 0.f;
  }

  int tile = blockIdx.x;
  if (tile >= ntiles) return;

  uint4 xr0, xr1, xr2, xr3;
#define LOADX(tl)                                                              \
  {                                                                            \
    int g, row, kk, gm;                                                        \
    const ushort* s;                                                           \
    g = t;            row = g >> 5; kk = (g & 31) ^ (row & 7);                 \
    gm = min((tl) * 64 + row, M - 1);                                          \
    s = (kk < 16) ? Xb + (size_t)gm * 128 + kk * 8                             \
                  : Gb + (size_t)gm * 128 + (kk - 16) * 8;                     \
    xr0 = *reinterpret_cast<const uint4*>(s);                                  \
    g = t + 512;      row = g >> 5; kk = (g & 31) ^ (row & 7);                 \
    gm = min((tl) * 64 + row, M - 1);                                          \
    s = (kk < 16) ? Xb + (size_t)gm * 128 + kk * 8                             \
                  : Gb + (size_t)gm * 128 + (kk - 16) * 8;                     \
    xr1 = *reinterpret_cast<const uint4*>(s);                                  \
    g = t + 1024;     row = g >> 5; kk = (g & 31) ^ (row & 7);                 \
    gm = min((tl) * 64 + row, M - 1);                                          \
    s = (kk < 16) ? Xb + (size_t)gm * 128 + kk * 8                             \
                  : Gb + (size_t)gm * 128 + (kk - 16) * 8;                     \
    xr2 = *reinterpret_cast<const uint4*>(s);                                  \
    g = t + 1536;     row = g >> 5; kk = (g & 31) ^ (row & 7);                 \
    gm = min((tl) * 64 + row, M - 1);                                          \
    s = (kk < 16) ? Xb + (size_t)gm * 128 + kk * 8                             \
                  : Gb + (size_t)gm * 128 + (kk - 16) * 8;                     \
    xr3 = *reinterpret_cast<const uint4*>(s);                                  \
  }
#define WRITEX()                                                               \
  {                                                                            \
    *reinterpret_cast<uint4*>(Xs + (size_t)t * 16) = xr0;                      \
    *reinterpret_cast<uint4*>(Xs + (size_t)(t + 512) * 16) = xr1;              \
    *reinterpret_cast<uint4*>(Xs + (size_t)(t + 1024) * 16) = xr2;             \
    *reinterpret_cast<uint4*>(Xs + (size_t)(t + 1536) * 16) = xr3;             \
  }

  LOADX(tile);
  WRITEX();
  __syncthreads();

  while (true) {
    int next = tile + gridDim.x;
    bool more = (next < ntiles);
    if (more) LOADX(next);

    f32x4 acc[2][2] = {};
#pragma unroll
    for (int ks = 0; ks < 8; ks++) {
      int ga = ks * 4 + (lane >> 4);
      short8 af[2], bf[2];
#pragma unroll
      for (int fm = 0; fm < 2; fm++) {
        int row = wm * 32 + fm * 16 + (lane & 15);
        af[fm] = *reinterpret_cast<const short8*>(
            Xs + row * 512 + ((ga ^ (row & 7)) << 4));
      }
#pragma unroll
      for (int fn = 0; fn < 2; fn++) {
        int colr = wn * 32 + fn * 16 + (lane & 15);
        bf[fn] = *reinterpret_cast<const short8*>(
            (char*)W1s + colr * 512 + ((ga ^ (colr & 7)) << 4));
      }
#pragma unroll
      for (int fm = 0; fm < 2; fm++)
#pragma unroll
        for (int fn = 0; fn < 2; fn++)
          acc[fm][fn] = __builtin_amdgcn_mfma_f32_16x16x32_bf16(
              af[fm], bf[fn], acc[fm][fn], 0, 0, 0);
    }

    __builtin_amdgcn_s_barrier();
    FENCE();

#pragma unroll
    for (int fn = 0; fn < 2; fn++) {
      int colg = wn * 32 + fn * 16 + (lane & 15);
      int gg = colg >> 3, cb = (colg & 7) * 2;
#pragma unroll
      for (int fm = 0; fm < 2; fm++) {
#pragma unroll
        for (int r = 0; r < 4; r++) {
          int rowl = wm * 32 + fm * 16 + (lane >> 4) * 4 + r;
          ushort hv = f2bf(fmaxf(acc[fm][fn][r] + bb1[fn], 0.f));
          *reinterpret_cast<ushort*>(
              Xs + rowl * 256 + ((gg ^ (rowl & 7)) << 4) + cb) = hv;
        }
      }
    }
    LGKM0();
    __builtin_amdgcn_s_barrier();
    FENCE();

    f32x4 acc2[2][2] = {};
#pragma unroll
    for (int ks = 0; ks < 4; ks++) {
      int gk = ks * 4 + (lane >> 4);
      short8 af[2], bf[2];
#pragma unroll
      for (int fm = 0; fm < 2; fm++) {
        int row = wm * 32 + fm * 16 + (lane & 15);
        af[fm] = *reinterpret_cast<const short8*>(
            Xs + row * 256 + ((gk ^ (row & 7)) << 4));
      }
#pragma unroll
      for (int fn = 0; fn < 2; fn++) {
        int colr = wn * 32 + fn * 16 + (lane & 15);
        bf[fn] = *reinterpret_cast<const short8*>(
            (char*)W2s + colr * 256 + ((gk ^ (colr & 7)) << 4));
      }
#pragma unroll
      for (int fm = 0; fm < 2; fm++)
#pragma unroll
        for (int fn = 0; fn < 2; fn++)
          acc2[fm][fn] = __builtin_amdgcn_mfma_f32_16x16x32_bf16(
              af[fm], bf[fn], acc2[fm][fn], 0, 0, 0);
    }

#pragma unroll
    for (int fn = 0; fn < 2; fn++) {
      int colg = wn * 32 + fn * 16 + (lane & 15);
#pragma unroll
      for (int fm = 0; fm < 2; fm++) {
#pragma unroll
        for (int r = 0; r < 4; r++) {
          int rowg = tile * 64 + wm * 32 + fm * 16 + (lane >> 4) * 4 + r;
          if (rowg >= M) continue;
          if (colg < 64) {
            float v = acc2[fm][fn][r];
            int b8 = __builtin_amdgcn_cvt_pk_fp8_f32(v, v, 0, false);
            P8[(size_t)rowg * 64 + colg] = (uchar)(b8 & 0xff);
          } else {
            S2[(size_t)rowg * 64 + (colg - 64)] = acc2[fm][fn][r] + bb2[fn];
          }
        }
      }
    }

    if (!more) break;
    __builtin_amdgcn_s_barrier();
    FENCE();
    WRITEX();
    LGKM0();
    __builtin_amdgcn_s_barrier();
    FENCE();
    tile = next;
  }
#undef LOADX
#undef WRITEX
}

extern "C" void kernel_launch(void* const* d_in, const int* in_sizes, int n_in,
                              void* d_out, int out_size, void* d_ws, size_t ws_size,
                              hipStream_t stream) {
  const float* h = (const float*)d_in[0];
  const int* esrc = (const int*)d_in[1];
  const int* edst = (const int*)d_in[2];
  const float* Ws1 = (const float*)d_in[3];
  const float* Wn1 = (const float*)d_in[4];
  const float* b1 = (const float*)d_in[5];
  const float* Ws2 = (const float*)d_in[6];
  const float* Wn2 = (const float*)d_in[7];
  const float* b2 = (const float*)d_in[8];
  float* out = (float*)d_out;

  const int N = in_sizes[0] / 128;  // 100000
  const int E = in_sizes[1];        // 1600000
  const int P = (N + 255) >> 8;     // 391 buckets (<=512)

  char* base = (char*)d_ws;
  size_t off = 0;
  auto alloc = [&](size_t bytes) {
    size_t o = off;
    off += (bytes + 255) & ~(size_t)255;
    return o;
  };
  int* deg = (int*)(base + alloc((size_t)N * 4));
  int* rs = (int*)(base + alloc((size_t)N * 4));
  int* bcnt = (int*)(base + alloc(513 * 4));
  int* bbase = (int*)(base + alloc(513 * 4));
  int* bcur = (int*)(base + alloc(513 * 4));
  uint* bed = (uint*)(base + alloc((size_t)E * 4));
  int* col = (int*)(base + alloc((size_t)E * 4));
  ushort* hb = (ushort*)(base + alloc((size_t)N * 128 * 2));
  uchar* h8 = (uchar*)(base + alloc((size_t)N * 128));
  ushort* aggb = (ushort*)(base + alloc((size_t)N * 128 * 2));
  ushort* Wt1 = (ushort*)(base + alloc(128 * 256 * 2));
  ushort* Wt2cat = (ushort*)(base + alloc(128 * 128 * 2));
  // overlays:
  uchar* p8 = (uchar*)bed;   // [N][64] fp8: bed dead after k_bcsr; N*64 <= E*4
  float* s2f = (float*)aggb; // [N][64] f32: row ranges owned by the writing tile

  const int NCH = (E + 8191) / 8192;
  const int NT = (N + 63) / 64;       // 1563 M-tiles
  const int n8 = N * 128 / 8;
  const int CB = (n8 + 255) / 256;    // cast blocks
  const int WB = (128 * 256 + 128 * 128) / 256;  // 192 weight blocks

  (void)hipMemsetAsync(bcnt, 0, 513 * 4, stream);
  k_bhist<<<NCH, 256, 0, stream>>>(edst, bcnt, E);
  k_bscan<<<1, 512, 0, stream>>>(bcnt, bbase, bcur, P, E);
  k_bscatter<<<NCH, 256, 0, stream>>>(edst, esrc, bcur, bed, E, P);
  k_bcsr<<<P, 256, 0, stream>>>(bed, bbase, deg, rs, col, N);

  k_prep<<<CB + WB, 256, 0, stream>>>(h, Ws1, Wn1, Ws2, Wn2, hb, h8, Wt1,
                                      Wt2cat, n8, CB);

  // Layer 1 aggregate, then persistent fused GEMM1+GEMM2 -> p2 (fp8) + s2 (f32)
  k_agg1<<<(N + 31) / 32, 256, 0, stream>>>(h8, col, rs, deg, aggb, N);
  k_persist<<<256, 512, 0, stream>>>(hb, aggb, Wt1, Wt2cat, b1, b2, p8, s2f, N, NT);
  // Layer 2 fused gather + add + relu
  k_agg_out<<<(N + 63) / 64, 256, 0, stream>>>(p8, s2f, col, rs, deg, out, N);
}

// Round 18
// 159.240 us; speedup vs baseline: 13.2226x; 1.0395x over previous
//
#include <hip/hip_runtime.h>

// GraphSAGE 2-layer (mean agg), N=100K, E=1.6M, 128->128->64, f32 in/out.
// R18 = R15/R17 config + (1) bscatter/bhist chunk 8192->4096 (grid 196->391
// blocks: was starving 60 of 256 CUs; LDS 56->32KB -> 4 blocks/CU) and
// (2) gather index-prefetch (next chunk's col[] loaded before current chunk's
// row conversion -- R13's proven pattern + R15's 8-loads-in-flight).
// Overlays: p8->bed (dead after CSR), s2f->aggb (tile-local rows, WAR-safe).

typedef __attribute__((ext_vector_type(8))) short short8;
typedef __attribute__((ext_vector_type(4))) float f32x4;
typedef __attribute__((ext_vector_type(2))) float f32x2;

__device__ __forceinline__ ushort f2bf(float f) {
  uint u = __float_as_uint(f);
  u += 0x7fffu + ((u >> 16) & 1u);  // round-to-nearest-even
  return (ushort)(u >> 16);
}

#define GLDS(src, dst)                                                        \
  __builtin_amdgcn_global_load_lds(                                           \
      (const __attribute__((address_space(1))) void*)(src),                   \
      (__attribute__((address_space(3))) void*)(dst), 16, 0, 0)

#define FENCE() asm volatile("" ::: "memory")
#define LGKM0() asm volatile("s_waitcnt lgkmcnt(0)" ::: "memory")

// ================= bucketed CSR build (4096-edge chunks) =================
__global__ __launch_bounds__(256) void k_bhist(const int* __restrict__ dst,
                                               int* __restrict__ bcnt, int E) {
  __shared__ int h[512];
  int t = threadIdx.x;
  for (int i = t; i < 512; i += 256) h[i] = 0;
  __syncthreads();
  int base = blockIdx.x * 4096;
  int end = min(base + 4096, E);
  for (int e = base + t; e < end; e += 256)
    atomicAdd(&h[((uint)dst[e]) >> 8], 1);
  __syncthreads();
  for (int i = t; i < 512; i += 256)
    if (h[i]) atomicAdd(&bcnt[i], h[i]);
}

__global__ __launch_bounds__(512) void k_bscan(const int* __restrict__ bcnt,
                                               int* __restrict__ bbase,
                                               int* __restrict__ bcur, int P, int E) {
  __shared__ int s[512];
  int t = threadIdx.x;
  int v = (t < P) ? bcnt[t] : 0;
  s[t] = v;
  __syncthreads();
  for (int off = 1; off < 512; off <<= 1) {
    int x = (t >= off) ? s[t - off] : 0;
    __syncthreads();
    s[t] += x;
    __syncthreads();
  }
  int ex = s[t] - v;
  if (t < P) {
    bbase[t] = ex;
    bcur[t] = ex;
  }
  if (t == P - 1) bbase[P] = E;
}

__global__ __launch_bounds__(256) void k_bscatter(const int* __restrict__ dst,
                                                  const int* __restrict__ src,
                                                  int* __restrict__ bcur,
                                                  uint* __restrict__ bed, int E, int P) {
  __shared__ int hist[512];
  __shared__ int incl[512];
  __shared__ int gpos[512];
  __shared__ int cur[512];
  __shared__ uint stage[4096];
  __shared__ ushort bof[4096];
  int t = threadIdx.x;
  int base = blockIdx.x * 4096;
  int cnt = min(4096, E - base);
  for (int i = t; i < 512; i += 256) hist[i] = 0;
  __syncthreads();
  for (int i = t; i < cnt; i += 256)
    atomicAdd(&hist[((uint)dst[base + i]) >> 8], 1);
  __syncthreads();
  incl[t] = hist[t];
  incl[t + 256] = hist[t + 256];
  __syncthreads();
  for (int off = 1; off < 512; off <<= 1) {
    int i0 = t, i1 = t + 256;
    int a0 = (i0 >= off) ? incl[i0 - off] : 0;
    int a1 = (i1 >= off) ? incl[i1 - off] : 0;
    __syncthreads();
    incl[i0] += a0;
    incl[i1] += a1;
    __syncthreads();
  }
  cur[t] = incl[t] - hist[t];
  cur[t + 256] = incl[t + 256] - hist[t + 256];
  for (int i = t; i < P; i += 256)
    if (hist[i]) gpos[i] = atomicAdd(&bcur[i], hist[i]);
  __syncthreads();
  for (int i = t; i < cnt; i += 256) {
    int d = dst[base + i];
    int b = ((uint)d) >> 8;
    uint val = (((uint)src[base + i]) << 8) | (uint)(d & 255);
    int slot = atomicAdd(&cur[b], 1);
    stage[slot] = val;
    bof[slot] = (ushort)b;
  }
  __syncthreads();
  for (int i = t; i < cnt; i += 256) {
    int b = bof[i];
    int ex = incl[b] - hist[b];
    bed[gpos[b] + (i - ex)] = stage[i];
  }
}

__global__ __launch_bounds__(256) void k_bcsr(const uint* __restrict__ bed,
                                              const int* __restrict__ bbase,
                                              int* __restrict__ deg,
                                              int* __restrict__ rs,
                                              int* __restrict__ col, int N) {
  __shared__ int dcnt[256];
  __shared__ int sofs[256];
  int b = blockIdx.x, t = threadIdx.x;
  int e0 = bbase[b], e1 = bbase[b + 1];
  dcnt[t] = 0;
  __syncthreads();
  for (int e = e0 + t; e < e1; e += 256) atomicAdd(&dcnt[bed[e] & 255u], 1);
  __syncthreads();
  int v0 = dcnt[t];
  sofs[t] = v0;
  __syncthreads();
  for (int off = 1; off < 256; off <<= 1) {
    int x = (t >= off) ? sofs[t - off] : 0;
    __syncthreads();
    sofs[t] += x;
    __syncthreads();
  }
  int ex = sofs[t] - v0;
  int node = (b << 8) + t;
  if (node < N) {
    deg[node] = v0;
    rs[node] = e0 + ex;
  }
  __syncthreads();
  dcnt[t] = e0 + ex;
  __syncthreads();
  for (int e = e0 + t; e < e1; e += 256) {
    uint v = bed[e];
    int pos = atomicAdd(&dcnt[v & 255u], 1);
    col[pos] = (int)(v >> 8);
  }
}

// -------- merged prep: cast h -> {bf16 hb, fp8 h8}; transpose W -> Wt1/Wt2cat
__global__ __launch_bounds__(256) void k_prep(
    const float* __restrict__ in, const float* __restrict__ Ws1,
    const float* __restrict__ Wn1, const float* __restrict__ Ws2,
    const float* __restrict__ Wn2, ushort* __restrict__ outb,
    uchar* __restrict__ out8, ushort* __restrict__ Wt1,
    ushort* __restrict__ Wt2cat, int n8, int CB) {
  if ((int)blockIdx.x < CB) {
    int i = blockIdx.x * 256 + threadIdx.x;
    if (i >= n8) return;
    const float4* p = reinterpret_cast<const float4*>(in) + i * 2;
    float4 a = p[0], b = p[1];
    ushort u[8];
    u[0] = f2bf(a.x); u[1] = f2bf(a.y); u[2] = f2bf(a.z); u[3] = f2bf(a.w);
    u[4] = f2bf(b.x); u[5] = f2bf(b.y); u[6] = f2bf(b.z); u[7] = f2bf(b.w);
    *reinterpret_cast<ulonglong2*>(outb + (size_t)i * 8) =
        *reinterpret_cast<ulonglong2*>(u);
    uint2 q;
    int w0 = __builtin_amdgcn_cvt_pk_fp8_f32(a.x, a.y, 0, false);
    w0 = __builtin_amdgcn_cvt_pk_fp8_f32(a.z, a.w, w0, true);
    int w1 = __builtin_amdgcn_cvt_pk_fp8_f32(b.x, b.y, 0, false);
    w1 = __builtin_amdgcn_cvt_pk_fp8_f32(b.z, b.w, w1, true);
    q.x = (uint)w0;
    q.y = (uint)w1;
    *reinterpret_cast<uint2*>(out8 + (size_t)i * 8) = q;
  } else {
    int idx = ((int)blockIdx.x - CB) * 256 + threadIdx.x;
    if (idx < 128 * 256) {
      int n = idx >> 8, k = idx & 255;
      float v = (k < 128) ? Ws1[(size_t)k * 128 + n]
                          : Wn1[(size_t)(k - 128) * 128 + n];
      Wt1[idx] = f2bf(v);
    } else if (idx < 128 * 256 + 128 * 128) {
      int j = idx - 128 * 256;
      int n = j >> 7, k = j & 127;
      float v = (n < 64) ? Wn2[(size_t)k * 64 + n] : Ws2[(size_t)k * 64 + (n - 64)];
      Wt2cat[j] = f2bf(v);
    }
  }
}

#define ACC16(v)                                                               \
  do {                                                                         \
    f32x2 f;                                                                   \
    f = __builtin_amdgcn_cvt_pk_f32_fp8((int)(v).x, false); a[0] += f.x; a[1] += f.y;  \
    f = __builtin_amdgcn_cvt_pk_f32_fp8((int)(v).x, true);  a[2] += f.x; a[3] += f.y;  \
    f = __builtin_amdgcn_cvt_pk_f32_fp8((int)(v).y, false); a[4] += f.x; a[5] += f.y;  \
    f = __builtin_amdgcn_cvt_pk_f32_fp8((int)(v).y, true);  a[6] += f.x; a[7] += f.y;  \
    f = __builtin_amdgcn_cvt_pk_f32_fp8((int)(v).z, false); a[8] += f.x; a[9] += f.y;  \
    f = __builtin_amdgcn_cvt_pk_f32_fp8((int)(v).z, true);  a[10] += f.x; a[11] += f.y;\
    f = __builtin_amdgcn_cvt_pk_f32_fp8((int)(v).w, false); a[12] += f.x; a[13] += f.y;\
    f = __builtin_amdgcn_cvt_pk_f32_fp8((int)(v).w, true);  a[14] += f.x; a[15] += f.y;\
  } while (0)

// -------- layer-1 aggregate: fp8 128B rows; 8-lane group per node ---------
// 8 row-loads in flight per chunk + next-chunk index prefetch.
__global__ __launch_bounds__(256) void k_agg1(const uchar* __restrict__ X8,
                                              const int* __restrict__ col,
                                              const int* __restrict__ rs,
                                              const int* __restrict__ deg,
                                              ushort* __restrict__ outb, int n) {
  int node = blockIdx.x * 32 + (threadIdx.x >> 3);
  if (node >= n) return;
  int sl = threadIdx.x & 7;
  int gbase = (threadIdx.x & 63) & ~7;
  int r0 = rs[node], d = deg[node];
  float a[16] = {};
  int j = 0;
  int myc = (sl < min(d, 8)) ? col[r0 + sl] : 0;
  while (j < d) {
    int cnt = min(d - j, 8);
    int nj = j + cnt;
    int ncnt = min(d - nj, 8);
    int c0 = __shfl(myc, gbase + 0, 64);
    int c1 = __shfl(myc, gbase + 1, 64);
    int c2 = __shfl(myc, gbase + 2, 64);
    int c3 = __shfl(myc, gbase + 3, 64);
    int c4 = __shfl(myc, gbase + 4, 64);
    int c5 = __shfl(myc, gbase + 5, 64);
    int c6 = __shfl(myc, gbase + 6, 64);
    int c7 = __shfl(myc, gbase + 7, 64);
    int nmyc = (sl < ncnt) ? col[r0 + nj + sl] : 0;  // prefetch next indices
    uint4 v0, v1, v2, v3, v4, v5, v6, v7;
    if (cnt > 0) v0 = *reinterpret_cast<const uint4*>(X8 + (size_t)c0 * 128 + sl * 16);
    if (cnt > 1) v1 = *reinterpret_cast<const uint4*>(X8 + (size_t)c1 * 128 + sl * 16);
    if (cnt > 2) v2 = *reinterpret_cast<const uint4*>(X8 + (size_t)c2 * 128 + sl * 16);
    if (cnt > 3) v3 = *reinterpret_cast<const uint4*>(X8 + (size_t)c3 * 128 + sl * 16);
    if (cnt > 4) v4 = *reinterpret_cast<const uint4*>(X8 + (size_t)c4 * 128 + sl * 16);
    if (cnt > 5) v5 = *reinterpret_cast<const uint4*>(X8 + (size_t)c5 * 128 + sl * 16);
    if (cnt > 6) v6 = *reinterpret_cast<const uint4*>(X8 + (size_t)c6 * 128 + sl * 16);
    if (cnt > 7) v7 = *reinterpret_cast<const uint4*>(X8 + (size_t)c7 * 128 + sl * 16);
    if (cnt > 0) ACC16(v0);
    if (cnt > 1) ACC16(v1);
    if (cnt > 2) ACC16(v2);
    if (cnt > 3) ACC16(v3);
    if (cnt > 4) ACC16(v4);
    if (cnt > 5) ACC16(v5);
    if (cnt > 6) ACC16(v6);
    if (cnt > 7) ACC16(v7);
    myc = nmyc;
    j = nj;
  }
  float rinv = 1.0f / fmaxf((float)d, 1.0f);
  ushort o[16];
#pragma unroll
  for (int k = 0; k < 16; k++) o[k] = f2bf(a[k] * rinv);
  ulonglong2* dst = reinterpret_cast<ulonglong2*>(outb + (size_t)node * 128 + sl * 16);
  dst[0] = reinterpret_cast<ulonglong2*>(o)[0];
  dst[1] = reinterpret_cast<ulonglong2*>(o)[1];
}

// -------- layer-2 fused gather+add: fp8 64B rows; 4-lane group per node ----
__global__ __launch_bounds__(256) void k_agg_out(const uchar* __restrict__ P8,
                                                 const float* __restrict__ S,
                                                 const int* __restrict__ col,
                                                 const int* __restrict__ rs,
                                                 const int* __restrict__ deg,
                                                 float* __restrict__ out, int n) {
  int node = blockIdx.x * 64 + (threadIdx.x >> 2);
  if (node >= n) return;
  int sl = threadIdx.x & 3;
  int gbase = (threadIdx.x & 63) & ~3;
  int r0 = rs[node], d = deg[node];
  float a[16] = {};
  int j = 0;
  int myc0 = (sl < min(d, 8)) ? col[r0 + sl] : 0;
  int myc1 = (sl + 4 < min(d, 8)) ? col[r0 + 4 + sl] : 0;
  while (j < d) {
    int cnt = min(d - j, 8);
    int nj = j + cnt;
    int ncnt = min(d - nj, 8);
    int c0 = __shfl(myc0, gbase + 0, 64);
    int c1 = __shfl(myc0, gbase + 1, 64);
    int c2 = __shfl(myc0, gbase + 2, 64);
    int c3 = __shfl(myc0, gbase + 3, 64);
    int c4 = __shfl(myc1, gbase + 0, 64);
    int c5 = __shfl(myc1, gbase + 1, 64);
    int c6 = __shfl(myc1, gbase + 2, 64);
    int c7 = __shfl(myc1, gbase + 3, 64);
    int nmyc0 = (sl < ncnt) ? col[r0 + nj + sl] : 0;        // prefetch
    int nmyc1 = (sl + 4 < ncnt) ? col[r0 + nj + 4 + sl] : 0;
    uint4 v0, v1, v2, v3, v4, v5, v6, v7;
    if (cnt > 0) v0 = *reinterpret_cast<const uint4*>(P8 + (size_t)c0 * 64 + sl * 16);
    if (cnt > 1) v1 = *reinterpret_cast<const uint4*>(P8 + (size_t)c1 * 64 + sl * 16);
    if (cnt > 2) v2 = *reinterpret_cast<const uint4*>(P8 + (size_t)c2 * 64 + sl * 16);
    if (cnt > 3) v3 = *reinterpret_cast<const uint4*>(P8 + (size_t)c3 * 64 + sl * 16);
    if (cnt > 4) v4 = *reinterpret_cast<const uint4*>(P8 + (size_t)c4 * 64 + sl * 16);
    if (cnt > 5) v5 = *reinterpret_cast<const uint4*>(P8 + (size_t)c5 * 64 + sl * 16);
    if (cnt > 6) v6 = *reinterpret_cast<const uint4*>(P8 + (size_t)c6 * 64 + sl * 16);
    if (cnt > 7) v7 = *reinterpret_cast<const uint4*>(P8 + (size_t)c7 * 64 + sl * 16);
    if (cnt > 0) ACC16(v0);
    if (cnt > 1) ACC16(v1);
    if (cnt > 2) ACC16(v2);
    if (cnt > 3) ACC16(v3);
    if (cnt > 4) ACC16(v4);
    if (cnt > 5) ACC16(v5);
    if (cnt > 6) ACC16(v6);
    if (cnt > 7) ACC16(v7);
    myc0 = nmyc0;
    myc1 = nmyc1;
    j = nj;
  }
  float rinv = 1.0f / fmaxf((float)d, 1.0f);
  const float4* sp = reinterpret_cast<const float4*>(S + (size_t)node * 64 + sl * 16);
  float4* op = reinterpret_cast<float4*>(out + (size_t)node * 64 + sl * 16);
#pragma unroll
  for (int q = 0; q < 4; q++) {
    float4 s = sp[q];
    float4 o;
    o.x = fmaxf(a[q * 4 + 0] * rinv + s.x, 0.f);
    o.y = fmaxf(a[q * 4 + 1] * rinv + s.y, 0.f);
    o.z = fmaxf(a[q * 4 + 2] * rinv + s.z, 0.f);
    o.w = fmaxf(a[q * 4 + 3] * rinv + s.w, 0.f);
    op[q] = o;
  }
}

// ---------------- PERSISTENT fused GEMM (v1, R11-proven) ----------------
__global__ __launch_bounds__(512) void k_persist(const ushort* __restrict__ Xb,
                                                 const ushort* __restrict__ Gb,
                                                 const ushort* __restrict__ Wt1,
                                                 const ushort* __restrict__ Wt2,
                                                 const float* __restrict__ b1,
                                                 const float* __restrict__ b2,
                                                 uchar* __restrict__ P8,
                                                 float* __restrict__ S2,
                                                 int M, int ntiles) {
  __shared__ ushort W1s[128 * 256];  // 64 KB
  __shared__ ushort W2s[128 * 128];  // 32 KB
  __shared__ char Xs[64 * 256 * 2];  // 32 KB X tile; h1 reuses [0,16KB)

  const int t = threadIdx.x;
  const int lane = t & 63;
  const int w = t >> 6;
  const int wm = w >> 2, wn = w & 3;

#pragma unroll
  for (int i = 0; i < 8; i++) {
    int g = t + 512 * i;
    int row = g >> 5, kph = g & 31;
    const ushort* src = Wt1 + (size_t)row * 256 + ((kph ^ (row & 7)) << 3);
    char* dst = (char*)W1s + ((g & ~63) << 4);
    GLDS(src, dst);
  }
#pragma unroll
  for (int i = 0; i < 4; i++) {
    int g = t + 512 * i;
    int row = g >> 4, kph = g & 15;
    const ushort* src = Wt2 + (size_t)row * 128 + ((kph ^ (row & 7)) << 3);
    char* dst = (char*)W2s + ((g & ~63) << 4);
    GLDS(src, dst);
  }

  float bb1[2], bb2[2];
#pragma unroll
  for (int fn = 0; fn < 2; fn++) {
    int colg = wn * 32 + fn * 16 + (lane & 15);
    bb1[fn] = b1[colg];
    bb2[fn] = (colg >= 64) ? b2[colg - 64] : 0.f;
  }

  int tile = blockIdx.x;
  if (tile >= ntiles) return;

  uint4 xr0, xr1, xr2, xr3;
#define LOADX(tl)                                                              \
  {                                                                            \
    int g, row, kk, gm;                                                        \
    const ushort* s;                                                           \
    g = t;            row = g >> 5; kk = (g & 31) ^ (row & 7);                 \
    gm = min((tl) * 64 + row, M - 1);                                          \
    s = (kk < 16) ? Xb + (size_t)gm * 128 + kk * 8                             \
                  : Gb + (size_t)gm * 128 + (kk - 16) * 8;                     \
    xr0 = *reinterpret_cast<const uint4*>(s);                                  \
    g = t + 512;      row = g >> 5; kk = (g & 31) ^ (row & 7);                 \
    gm = min((tl) * 64 + row, M - 1);                                          \
    s = (kk < 16) ? Xb + (size_t)gm * 128 + kk * 8                             \
                  : Gb + (size_t)gm * 128 + (kk - 16) * 8;                     \
    xr1 = *reinterpret_cast<const uint4*>(s);                                  \
    g = t + 1024;     row = g >> 5; kk = (g & 31) ^ (row & 7);                 \
    gm = min((tl) * 64 + row, M - 1);                                          \
    s = (kk < 16) ? Xb + (size_t)gm * 128 + kk * 8                             \
                  : Gb + (size_t)gm * 128 + (kk - 16) * 8;                     \
    xr2 = *reinterpret_cast<const uint4*>(s);                                  \
    g = t + 1536;     row = g >> 5; kk = (g & 31) ^ (row & 7);                 \
    gm = min((tl) * 64 + row, M - 1);                                          \
    s = (kk < 16) ? Xb + (size_t)gm * 128 + kk * 8                             \
                  : Gb + (size_t)gm * 128 + (kk - 16) * 8;                     \
    xr3 = *reinterpret_cast<const uint4*>(s);                                  \
  }
#define WRITEX()                                                               \
  {                                                                            \
    *reinterpret_cast<uint4*>(Xs + (size_t)t * 16) = xr0;                      \
    *reinterpret_cast<uint4*>(Xs + (size_t)(t + 512) * 16) = xr1;              \
    *reinterpret_cast<uint4*>(Xs + (size_t)(t + 1024) * 16) = xr2;             \
    *reinterpret_cast<uint4*>(Xs + (size_t)(t + 1536) * 16) = xr3;             \
  }

  LOADX(tile);
  WRITEX();
  __syncthreads();

  while (true) {
    int next = tile + gridDim.x;
    bool more = (next < ntiles);
    if (more) LOADX(next);

    f32x4 acc[2][2] = {};
#pragma unroll
    for (int ks = 0; ks < 8; ks++) {
      int ga = ks * 4 + (lane >> 4);
      short8 af[2], bf[2];
#pragma unroll
      for (int fm = 0; fm < 2; fm++) {
        int row = wm * 32 + fm * 16 + (lane & 15);
        af[fm] = *reinterpret_cast<const short8*>(
            Xs + row * 512 + ((ga ^ (row & 7)) << 4));
      }
#pragma unroll
      for (int fn = 0; fn < 2; fn++) {
        int colr = wn * 32 + fn * 16 + (lane & 15);
        bf[fn] = *reinterpret_cast<const short8*>(
            (char*)W1s + colr * 512 + ((ga ^ (colr & 7)) << 4));
      }
#pragma unroll
      for (int fm = 0; fm < 2; fm++)
#pragma unroll
        for (int fn = 0; fn < 2; fn++)
          acc[fm][fn] = __builtin_amdgcn_mfma_f32_16x16x32_bf16(
              af[fm], bf[fn], acc[fm][fn], 0, 0, 0);
    }

    __builtin_amdgcn_s_barrier();
    FENCE();

#pragma unroll
    for (int fn = 0; fn < 2; fn++) {
      int colg = wn * 32 + fn * 16 + (lane & 15);
      int gg = colg >> 3, cb = (colg & 7) * 2;
#pragma unroll
      for (int fm = 0; fm < 2; fm++) {
#pragma unroll
        for (int r = 0; r < 4; r++) {
          int rowl = wm * 32 + fm * 16 + (lane >> 4) * 4 + r;
          ushort hv = f2bf(fmaxf(acc[fm][fn][r] + bb1[fn], 0.f));
          *reinterpret_cast<ushort*>(
              Xs + rowl * 256 + ((gg ^ (rowl & 7)) << 4) + cb) = hv;
        }
      }
    }
    LGKM0();
    __builtin_amdgcn_s_barrier();
    FENCE();

    f32x4 acc2[2][2] = {};
#pragma unroll
    for (int ks = 0; ks < 4; ks++) {
      int gk = ks * 4 + (lane >> 4);
      short8 af[2], bf[2];
#pragma unroll
      for (int fm = 0; fm < 2; fm++) {
        int row = wm * 32 + fm * 16 + (lane & 15);
        af[fm] = *reinterpret_cast<const short8*>(
            Xs + row * 256 + ((gk ^ (row & 7)) << 4));
      }
#pragma unroll
      for (int fn = 0; fn < 2; fn++) {
        int colr = wn * 32 + fn * 16 + (lane & 15);
        bf[fn] = *reinterpret_cast<const short8*>(
            (char*)W2s + colr * 256 + ((gk ^ (colr & 7)) << 4));
      }
#pragma unroll
      for (int fm = 0; fm < 2; fm++)
#pragma unroll
        for (int fn = 0; fn < 2; fn++)
          acc2[fm][fn] = __builtin_amdgcn_mfma_f32_16x16x32_bf16(
              af[fm], bf[fn], acc2[fm][fn], 0, 0, 0);
    }

#pragma unroll
    for (int fn = 0; fn < 2; fn++) {
      int colg = wn * 32 + fn * 16 + (lane & 15);
#pragma unroll
      for (int fm = 0; fm < 2; fm++) {
#pragma unroll
        for (int r = 0; r < 4; r++) {
          int rowg = tile * 64 + wm * 32 + fm * 16 + (lane >> 4) * 4 + r;
          if (rowg >= M) continue;
          if (colg < 64) {
            float v = acc2[fm][fn][r];
            int b8 = __builtin_amdgcn_cvt_pk_fp8_f32(v, v, 0, false);
            P8[(size_t)rowg * 64 + colg] = (uchar)(b8 & 0xff);
          } else {
            S2[(size_t)rowg * 64 + (colg - 64)] = acc2[fm][fn][r] + bb2[fn];
          }
        }
      }
    }

    if (!more) break;
    __builtin_amdgcn_s_barrier();
    FENCE();
    WRITEX();
    LGKM0();
    __builtin_amdgcn_s_barrier();
    FENCE();
    tile = next;
  }
#undef LOADX
#undef WRITEX
}

extern "C" void kernel_launch(void* const* d_in, const int* in_sizes, int n_in,
                              void* d_out, int out_size, void* d_ws, size_t ws_size,
                              hipStream_t stream) {
  const float* h = (const float*)d_in[0];
  const int* esrc = (const int*)d_in[1];
  const int* edst = (const int*)d_in[2];
  const float* Ws1 = (const float*)d_in[3];
  const float* Wn1 = (const float*)d_in[4];
  const float* b1 = (const float*)d_in[5];
  const float* Ws2 = (const float*)d_in[6];
  const float* Wn2 = (const float*)d_in[7];
  const float* b2 = (const float*)d_in[8];
  float* out = (float*)d_out;

  const int N = in_sizes[0] / 128;  // 100000
  const int E = in_sizes[1];        // 1600000
  const int P = (N + 255) >> 8;     // 391 buckets (<=512)

  char* base = (char*)d_ws;
  size_t off = 0;
  auto alloc = [&](size_t bytes) {
    size_t o = off;
    off += (bytes + 255) & ~(size_t)255;
    return o;
  };
  int* deg = (int*)(base + alloc((size_t)N * 4));
  int* rs = (int*)(base + alloc((size_t)N * 4));
  int* bcnt = (int*)(base + alloc(513 * 4));
  int* bbase = (int*)(base + alloc(513 * 4));
  int* bcur = (int*)(base + alloc(513 * 4));
  uint* bed = (uint*)(base + alloc((size_t)E * 4));
  int* col = (int*)(base + alloc((size_t)E * 4));
  ushort* hb = (ushort*)(base + alloc((size_t)N * 128 * 2));
  uchar* h8 = (uchar*)(base + alloc((size_t)N * 128));
  ushort* aggb = (ushort*)(base + alloc((size_t)N * 128 * 2));
  ushort* Wt1 = (ushort*)(base + alloc(128 * 256 * 2));
  ushort* Wt2cat = (ushort*)(base + alloc(128 * 128 * 2));
  // overlays:
  uchar* p8 = (uchar*)bed;   // [N][64] fp8: bed dead after k_bcsr; N*64 <= E*4
  float* s2f = (float*)aggb; // [N][64] f32: row ranges owned by the writing tile

  const int NCH = (E + 4095) / 4096;  // 391 edge chunks
  const int NT = (N + 63) / 64;       // 1563 M-tiles
  const int n8 = N * 128 / 8;
  const int CB = (n8 + 255) / 256;    // cast blocks
  const int WB = (128 * 256 + 128 * 128) / 256;  // 192 weight blocks

  (void)hipMemsetAsync(bcnt, 0, 513 * 4, stream);
  k_bhist<<<NCH, 256, 0, stream>>>(edst, bcnt, E);
  k_bscan<<<1, 512, 0, stream>>>(bcnt, bbase, bcur, P, E);
  k_bscatter<<<NCH, 256, 0, stream>>>(edst, esrc, bcur, bed, E, P);
  k_bcsr<<<P, 256, 0, stream>>>(bed, bbase, deg, rs, col, N);

  k_prep<<<CB + WB, 256, 0, stream>>>(h, Ws1, Wn1, Ws2, Wn2, hb, h8, Wt1,
                                      Wt2cat, n8, CB);

  // Layer 1 aggregate, then persistent fused GEMM1+GEMM2 -> p2 (fp8) + s2 (f32)
  k_agg1<<<(N + 31) / 32, 256, 0, stream>>>(h8, col, rs, deg, aggb, N);
  k_persist<<<256, 512, 0, stream>>>(hb, aggb, Wt1, Wt2cat, b1, b2, p8, s2f, N, NT);
  // Layer 2 fused gather + add + relu
  k_agg_out<<<(N + 63) / 64, 256, 0, stream>>>(p8, s2f, col, rs, deg, out, N);
}

// Round 19
// 156.172 us; speedup vs baseline: 13.4824x; 1.0196x over previous
//
#include <hip/hip_runtime.h>

// GraphSAGE 2-layer (mean agg), N=100K, E=1.6M, 128->128->64, f32 in/out.
// R19 = R18 + k_persist v3: BM=32, W2 in registers (B-frags, 4 short8),
// LDS = W1s 64KB + Xs 16KB = 80KB -> 2 blocks/CU (16 waves/CU, was 8):
// cross-block wave overlap hides the 4 barrier-phases/tile (m114 mechanism).
// v1 epilogue layout + W1-in-LDS + grid-stride reg-prefetch preserved.
// Overlays: p8->bed (dead after CSR), s2f->aggb (tile-local rows, WAR-safe).

typedef __attribute__((ext_vector_type(8))) short short8;
typedef __attribute__((ext_vector_type(4))) float f32x4;
typedef __attribute__((ext_vector_type(2))) float f32x2;

__device__ __forceinline__ ushort f2bf(float f) {
  uint u = __float_as_uint(f);
  u += 0x7fffu + ((u >> 16) & 1u);  // round-to-nearest-even
  return (ushort)(u >> 16);
}

#define GLDS(src, dst)                                                        \
  __builtin_amdgcn_global_load_lds(                                           \
      (const __attribute__((address_space(1))) void*)(src),                   \
      (__attribute__((address_space(3))) void*)(dst), 16, 0, 0)

#define FENCE() asm volatile("" ::: "memory")
#define LGKM0() asm volatile("s_waitcnt lgkmcnt(0)" ::: "memory")

// ================= bucketed CSR build (4096-edge chunks) =================
__global__ __launch_bounds__(256) void k_bhist(const int* __restrict__ dst,
                                               int* __restrict__ bcnt, int E) {
  __shared__ int h[512];
  int t = threadIdx.x;
  for (int i = t; i < 512; i += 256) h[i] = 0;
  __syncthreads();
  int base = blockIdx.x * 4096;
  int end = min(base + 4096, E);
  for (int e = base + t; e < end; e += 256)
    atomicAdd(&h[((uint)dst[e]) >> 8], 1);
  __syncthreads();
  for (int i = t; i < 512; i += 256)
    if (h[i]) atomicAdd(&bcnt[i], h[i]);
}

__global__ __launch_bounds__(512) void k_bscan(const int* __restrict__ bcnt,
                                               int* __restrict__ bbase,
                                               int* __restrict__ bcur, int P, int E) {
  __shared__ int s[512];
  int t = threadIdx.x;
  int v = (t < P) ? bcnt[t] : 0;
  s[t] = v;
  __syncthreads();
  for (int off = 1; off < 512; off <<= 1) {
    int x = (t >= off) ? s[t - off] : 0;
    __syncthreads();
    s[t] += x;
    __syncthreads();
  }
  int ex = s[t] - v;
  if (t < P) {
    bbase[t] = ex;
    bcur[t] = ex;
  }
  if (t == P - 1) bbase[P] = E;
}

__global__ __launch_bounds__(256) void k_bscatter(const int* __restrict__ dst,
                                                  const int* __restrict__ src,
                                                  int* __restrict__ bcur,
                                                  uint* __restrict__ bed, int E, int P) {
  __shared__ int hist[512];
  __shared__ int incl[512];
  __shared__ int gpos[512];
  __shared__ int cur[512];
  __shared__ uint stage[4096];
  __shared__ ushort bof[4096];
  int t = threadIdx.x;
  int base = blockIdx.x * 4096;
  int cnt = min(4096, E - base);
  for (int i = t; i < 512; i += 256) hist[i] = 0;
  __syncthreads();
  for (int i = t; i < cnt; i += 256)
    atomicAdd(&hist[((uint)dst[base + i]) >> 8], 1);
  __syncthreads();
  incl[t] = hist[t];
  incl[t + 256] = hist[t + 256];
  __syncthreads();
  for (int off = 1; off < 512; off <<= 1) {
    int i0 = t, i1 = t + 256;
    int a0 = (i0 >= off) ? incl[i0 - off] : 0;
    int a1 = (i1 >= off) ? incl[i1 - off] : 0;
    __syncthreads();
    incl[i0] += a0;
    incl[i1] += a1;
    __syncthreads();
  }
  cur[t] = incl[t] - hist[t];
  cur[t + 256] = incl[t + 256] - hist[t + 256];
  for (int i = t; i < P; i += 256)
    if (hist[i]) gpos[i] = atomicAdd(&bcur[i], hist[i]);
  __syncthreads();
  for (int i = t; i < cnt; i += 256) {
    int d = dst[base + i];
    int b = ((uint)d) >> 8;
    uint val = (((uint)src[base + i]) << 8) | (uint)(d & 255);
    int slot = atomicAdd(&cur[b], 1);
    stage[slot] = val;
    bof[slot] = (ushort)b;
  }
  __syncthreads();
  for (int i = t; i < cnt; i += 256) {
    int b = bof[i];
    int ex = incl[b] - hist[b];
    bed[gpos[b] + (i - ex)] = stage[i];
  }
}

__global__ __launch_bounds__(256) void k_bcsr(const uint* __restrict__ bed,
                                              const int* __restrict__ bbase,
                                              int* __restrict__ deg,
                                              int* __restrict__ rs,
                                              int* __restrict__ col, int N) {
  __shared__ int dcnt[256];
  __shared__ int sofs[256];
  int b = blockIdx.x, t = threadIdx.x;
  int e0 = bbase[b], e1 = bbase[b + 1];
  dcnt[t] = 0;
  __syncthreads();
  for (int e = e0 + t; e < e1; e += 256) atomicAdd(&dcnt[bed[e] & 255u], 1);
  __syncthreads();
  int v0 = dcnt[t];
  sofs[t] = v0;
  __syncthreads();
  for (int off = 1; off < 256; off <<= 1) {
    int x = (t >= off) ? sofs[t - off] : 0;
    __syncthreads();
    sofs[t] += x;
    __syncthreads();
  }
  int ex = sofs[t] - v0;
  int node = (b << 8) + t;
  if (node < N) {
    deg[node] = v0;
    rs[node] = e0 + ex;
  }
  __syncthreads();
  dcnt[t] = e0 + ex;
  __syncthreads();
  for (int e = e0 + t; e < e1; e += 256) {
    uint v = bed[e];
    int pos = atomicAdd(&dcnt[v & 255u], 1);
    col[pos] = (int)(v >> 8);
  }
}

// -------- merged prep: cast h -> {bf16 hb, fp8 h8}; transpose W -> Wt1/Wt2cat
__global__ __launch_bounds__(256) void k_prep(
    const float* __restrict__ in, const float* __restrict__ Ws1,
    const float* __restrict__ Wn1, const float* __restrict__ Ws2,
    const float* __restrict__ Wn2, ushort* __restrict__ outb,
    uchar* __restrict__ out8, ushort* __restrict__ Wt1,
    ushort* __restrict__ Wt2cat, int n8, int CB) {
  if ((int)blockIdx.x < CB) {
    int i = blockIdx.x * 256 + threadIdx.x;
    if (i >= n8) return;
    const float4* p = reinterpret_cast<const float4*>(in) + i * 2;
    float4 a = p[0], b = p[1];
    ushort u[8];
    u[0] = f2bf(a.x); u[1] = f2bf(a.y); u[2] = f2bf(a.z); u[3] = f2bf(a.w);
    u[4] = f2bf(b.x); u[5] = f2bf(b.y); u[6] = f2bf(b.z); u[7] = f2bf(b.w);
    *reinterpret_cast<ulonglong2*>(outb + (size_t)i * 8) =
        *reinterpret_cast<ulonglong2*>(u);
    uint2 q;
    int w0 = __builtin_amdgcn_cvt_pk_fp8_f32(a.x, a.y, 0, false);
    w0 = __builtin_amdgcn_cvt_pk_fp8_f32(a.z, a.w, w0, true);
    int w1 = __builtin_amdgcn_cvt_pk_fp8_f32(b.x, b.y, 0, false);
    w1 = __builtin_amdgcn_cvt_pk_fp8_f32(b.z, b.w, w1, true);
    q.x = (uint)w0;
    q.y = (uint)w1;
    *reinterpret_cast<uint2*>(out8 + (size_t)i * 8) = q;
  } else {
    int idx = ((int)blockIdx.x - CB) * 256 + threadIdx.x;
    if (idx < 128 * 256) {
      int n = idx >> 8, k = idx & 255;
      float v = (k < 128) ? Ws1[(size_t)k * 128 + n]
                          : Wn1[(size_t)(k - 128) * 128 + n];
      Wt1[idx] = f2bf(v);
    } else if (idx < 128 * 256 + 128 * 128) {
      int j = idx - 128 * 256;
      int n = j >> 7, k = j & 127;
      float v = (n < 64) ? Wn2[(size_t)k * 64 + n] : Ws2[(size_t)k * 64 + (n - 64)];
      Wt2cat[j] = f2bf(v);
    }
  }
}

#define ACC16(v)                                                               \
  do {                                                                         \
    f32x2 f;                                                                   \
    f = __builtin_amdgcn_cvt_pk_f32_fp8((int)(v).x, false); a[0] += f.x; a[1] += f.y;  \
    f = __builtin_amdgcn_cvt_pk_f32_fp8((int)(v).x, true);  a[2] += f.x; a[3] += f.y;  \
    f = __builtin_amdgcn_cvt_pk_f32_fp8((int)(v).y, false); a[4] += f.x; a[5] += f.y;  \
    f = __builtin_amdgcn_cvt_pk_f32_fp8((int)(v).y, true);  a[6] += f.x; a[7] += f.y;  \
    f = __builtin_amdgcn_cvt_pk_f32_fp8((int)(v).z, false); a[8] += f.x; a[9] += f.y;  \
    f = __builtin_amdgcn_cvt_pk_f32_fp8((int)(v).z, true);  a[10] += f.x; a[11] += f.y;\
    f = __builtin_amdgcn_cvt_pk_f32_fp8((int)(v).w, false); a[12] += f.x; a[13] += f.y;\
    f = __builtin_amdgcn_cvt_pk_f32_fp8((int)(v).w, true);  a[14] += f.x; a[15] += f.y;\
  } while (0)

// -------- layer-1 aggregate: fp8 128B rows; 8-lane group per node ---------
__global__ __launch_bounds__(256) void k_agg1(const uchar* __restrict__ X8,
                                              const int* __restrict__ col,
                                              const int* __restrict__ rs,
                                              const int* __restrict__ deg,
                                              ushort* __restrict__ outb, int n) {
  int node = blockIdx.x * 32 + (threadIdx.x >> 3);
  if (node >= n) return;
  int sl = threadIdx.x & 7;
  int gbase = (threadIdx.x & 63) & ~7;
  int r0 = rs[node], d = deg[node];
  float a[16] = {};
  int j = 0;
  int myc = (sl < min(d, 8)) ? col[r0 + sl] : 0;
  while (j < d) {
    int cnt = min(d - j, 8);
    int nj = j + cnt;
    int ncnt = min(d - nj, 8);
    int c0 = __shfl(myc, gbase + 0, 64);
    int c1 = __shfl(myc, gbase + 1, 64);
    int c2 = __shfl(myc, gbase + 2, 64);
    int c3 = __shfl(myc, gbase + 3, 64);
    int c4 = __shfl(myc, gbase + 4, 64);
    int c5 = __shfl(myc, gbase + 5, 64);
    int c6 = __shfl(myc, gbase + 6, 64);
    int c7 = __shfl(myc, gbase + 7, 64);
    int nmyc = (sl < ncnt) ? col[r0 + nj + sl] : 0;  // prefetch next indices
    uint4 v0, v1, v2, v3, v4, v5, v6, v7;
    if (cnt > 0) v0 = *reinterpret_cast<const uint4*>(X8 + (size_t)c0 * 128 + sl * 16);
    if (cnt > 1) v1 = *reinterpret_cast<const uint4*>(X8 + (size_t)c1 * 128 + sl * 16);
    if (cnt > 2) v2 = *reinterpret_cast<const uint4*>(X8 + (size_t)c2 * 128 + sl * 16);
    if (cnt > 3) v3 = *reinterpret_cast<const uint4*>(X8 + (size_t)c3 * 128 + sl * 16);
    if (cnt > 4) v4 = *reinterpret_cast<const uint4*>(X8 + (size_t)c4 * 128 + sl * 16);
    if (cnt > 5) v5 = *reinterpret_cast<const uint4*>(X8 + (size_t)c5 * 128 + sl * 16);
    if (cnt > 6) v6 = *reinterpret_cast<const uint4*>(X8 + (size_t)c6 * 128 + sl * 16);
    if (cnt > 7) v7 = *reinterpret_cast<const uint4*>(X8 + (size_t)c7 * 128 + sl * 16);
    if (cnt > 0) ACC16(v0);
    if (cnt > 1) ACC16(v1);
    if (cnt > 2) ACC16(v2);
    if (cnt > 3) ACC16(v3);
    if (cnt > 4) ACC16(v4);
    if (cnt > 5) ACC16(v5);
    if (cnt > 6) ACC16(v6);
    if (cnt > 7) ACC16(v7);
    myc = nmyc;
    j = nj;
  }
  float rinv = 1.0f / fmaxf((float)d, 1.0f);
  ushort o[16];
#pragma unroll
  for (int k = 0; k < 16; k++) o[k] = f2bf(a[k] * rinv);
  ulonglong2* dst = reinterpret_cast<ulonglong2*>(outb + (size_t)node * 128 + sl * 16);
  dst[0] = reinterpret_cast<ulonglong2*>(o)[0];
  dst[1] = reinterpret_cast<ulonglong2*>(o)[1];
}

// -------- layer-2 fused gather+add: fp8 64B rows; 4-lane group per node ----
__global__ __launch_bounds__(256) void k_agg_out(const uchar* __restrict__ P8,
                                                 const float* __restrict__ S,
                                                 const int* __restrict__ col,
                                                 const int* __restrict__ rs,
                                                 const int* __restrict__ deg,
                                                 float* __restrict__ out, int n) {
  int node = blockIdx.x * 64 + (threadIdx.x >> 2);
  if (node >= n) return;
  int sl = threadIdx.x & 3;
  int gbase = (threadIdx.x & 63) & ~3;
  int r0 = rs[node], d = deg[node];
  float a[16] = {};
  int j = 0;
  int myc0 = (sl < min(d, 8)) ? col[r0 + sl] : 0;
  int myc1 = (sl + 4 < min(d, 8)) ? col[r0 + 4 + sl] : 0;
  while (j < d) {
    int cnt = min(d - j, 8);
    int nj = j + cnt;
    int ncnt = min(d - nj, 8);
    int c0 = __shfl(myc0, gbase + 0, 64);
    int c1 = __shfl(myc0, gbase + 1, 64);
    int c2 = __shfl(myc0, gbase + 2, 64);
    int c3 = __shfl(myc0, gbase + 3, 64);
    int c4 = __shfl(myc1, gbase + 0, 64);
    int c5 = __shfl(myc1, gbase + 1, 64);
    int c6 = __shfl(myc1, gbase + 2, 64);
    int c7 = __shfl(myc1, gbase + 3, 64);
    int nmyc0 = (sl < ncnt) ? col[r0 + nj + sl] : 0;        // prefetch
    int nmyc1 = (sl + 4 < ncnt) ? col[r0 + nj + 4 + sl] : 0;
    uint4 v0, v1, v2, v3, v4, v5, v6, v7;
    if (cnt > 0) v0 = *reinterpret_cast<const uint4*>(P8 + (size_t)c0 * 64 + sl * 16);
    if (cnt > 1) v1 = *reinterpret_cast<const uint4*>(P8 + (size_t)c1 * 64 + sl * 16);
    if (cnt > 2) v2 = *reinterpret_cast<const uint4*>(P8 + (size_t)c2 * 64 + sl * 16);
    if (cnt > 3) v3 = *reinterpret_cast<const uint4*>(P8 + (size_t)c3 * 64 + sl * 16);
    if (cnt > 4) v4 = *reinterpret_cast<const uint4*>(P8 + (size_t)c4 * 64 + sl * 16);
    if (cnt > 5) v5 = *reinterpret_cast<const uint4*>(P8 + (size_t)c5 * 64 + sl * 16);
    if (cnt > 6) v6 = *reinterpret_cast<const uint4*>(P8 + (size_t)c6 * 64 + sl * 16);
    if (cnt > 7) v7 = *reinterpret_cast<const uint4*>(P8 + (size_t)c7 * 64 + sl * 16);
    if (cnt > 0) ACC16(v0);
    if (cnt > 1) ACC16(v1);
    if (cnt > 2) ACC16(v2);
    if (cnt > 3) ACC16(v3);
    if (cnt > 4) ACC16(v4);
    if (cnt > 5) ACC16(v5);
    if (cnt > 6) ACC16(v6);
    if (cnt > 7) ACC16(v7);
    myc0 = nmyc0;
    myc1 = nmyc1;
    j = nj;
  }
  float rinv = 1.0f / fmaxf((float)d, 1.0f);
  const float4* sp = reinterpret_cast<const float4*>(S + (size_t)node * 64 + sl * 16);
  float4* op = reinterpret_cast<float4*>(out + (size_t)node * 64 + sl * 16);
#pragma unroll
  for (int q = 0; q < 4; q++) {
    float4 s = sp[q];
    float4 o;
    o.x = fmaxf(a[q * 4 + 0] * rinv + s.x, 0.f);
    o.y = fmaxf(a[q * 4 + 1] * rinv + s.y, 0.f);
    o.z = fmaxf(a[q * 4 + 2] * rinv + s.z, 0.f);
    o.w = fmaxf(a[q * 4 + 3] * rinv + s.w, 0.f);
    op[q] = o;
  }
}

// ---------------- PERSISTENT fused GEMM v3 (BM=32, 2 blocks/CU) ------------
// 512 blocks x 512 thr; 8 waves = 8 col-octants (wn 0..7, 16 cols each).
// W1 in LDS (64KB), W2 B-frags in regs (4 short8), Xs 16KB -> 80KB total.
__global__ __launch_bounds__(512, 4) void k_persist(
    const ushort* __restrict__ Xb, const ushort* __restrict__ Gb,
    const ushort* __restrict__ Wt1, const ushort* __restrict__ Wt2,
    const float* __restrict__ b1, const float* __restrict__ b2,
    uchar* __restrict__ P8, float* __restrict__ S2, int M, int ntiles) {
  __shared__ ushort W1s[128 * 256];  // 64 KB
  __shared__ char Xs[32 * 512];      // 16 KB X tile; h1 reuses [0,8KB)

  const int t = threadIdx.x;
  const int lane = t & 63;
  const int wn = t >> 6;  // col octant 0..7
  const int l15 = lane & 15;
  const int grp = lane >> 4;

#pragma unroll
  for (int i = 0; i < 8; i++) {
    int g = t + 512 * i;
    int row = g >> 5, kph = g & 31;
    const ushort* src = Wt1 + (size_t)row * 256 + ((kph ^ (row & 7)) << 3);
    char* dst = (char*)W1s + ((g & ~63) << 4);
    GLDS(src, dst);
  }

  // W2 B-fragments in registers (colr fixed per thread)
  const int colg = wn * 16 + l15;
  short8 w2f[4];
#pragma unroll
  for (int ks = 0; ks < 4; ks++) {
    int gk = ks * 4 + grp;
    w2f[ks] = *reinterpret_cast<const short8*>(Wt2 + (size_t)colg * 128 + gk * 8);
  }

  const float bb1 = b1[colg];
  const float bb2 = (colg >= 64) ? b2[colg - 64] : 0.f;

  int tile = blockIdx.x;
  if (tile >= ntiles) return;

  uint4 xr0, xr1;
#define LOADX(tl)                                                              \
  {                                                                            \
    int g, row, kk, gm;                                                        \
    const ushort* s;                                                           \
    g = t;        row = g >> 5; kk = (g & 31) ^ (row & 7);                     \
    gm = min((tl) * 32 + row, M - 1);                                          \
    s = (kk < 16) ? Xb + (size_t)gm * 128 + kk * 8                             \
                  : Gb + (size_t)gm * 128 + (kk - 16) * 8;                     \
    xr0 = *reinterpret_cast<const uint4*>(s);                                  \
    g = t + 512;  row = g >> 5; kk = (g & 31) ^ (row & 7);                     \
    gm = min((tl) * 32 + row, M - 1);                                          \
    s = (kk < 16) ? Xb + (size_t)gm * 128 + kk * 8                             \
                  : Gb + (size_t)gm * 128 + (kk - 16) * 8;                     \
    xr1 = *reinterpret_cast<const uint4*>(s);                                  \
  }
#define WRITEX()                                                               \
  {                                                                            \
    *reinterpret_cast<uint4*>(Xs + (size_t)t * 16) = xr0;                      \
    *reinterpret_cast<uint4*>(Xs + (size_t)(t + 512) * 16) = xr1;              \
  }

  LOADX(tile);
  WRITEX();
  __syncthreads();

  while (true) {
    int next = tile + gridDim.x;
    bool more = (next < ntiles);
    if (more) LOADX(next);

    // ---- GEMM1: 32 rows x 16 cols per wave, K=256 ----
    f32x4 acc[2] = {};
#pragma unroll
    for (int ks = 0; ks < 8; ks++) {
      int ga = ks * 4 + grp;
      short8 af[2], bf;
#pragma unroll
      for (int fm = 0; fm < 2; fm++) {
        int row = fm * 16 + l15;
        af[fm] = *reinterpret_cast<const short8*>(
            Xs + row * 512 + ((ga ^ (row & 7)) << 4));
      }
      bf = *reinterpret_cast<const short8*>(
          (char*)W1s + colg * 512 + ((ga ^ (colg & 7)) << 4));
#pragma unroll
      for (int fm = 0; fm < 2; fm++)
        acc[fm] = __builtin_amdgcn_mfma_f32_16x16x32_bf16(af[fm], bf, acc[fm],
                                                          0, 0, 0);
    }

    __builtin_amdgcn_s_barrier();  // X reads done (WAR before h1 write)
    FENCE();

    // ---- epi1: h1 -> Xs[0,8KB), 256B rows, swizzled b16 writes ----
    {
      int gg = colg >> 3, cb = (colg & 7) * 2;
#pragma unroll
      for (int fm = 0; fm < 2; fm++) {
#pragma unroll
        for (int r = 0; r < 4; r++) {
          int rowl = fm * 16 + grp * 4 + r;
          ushort hv = f2bf(fmaxf(acc[fm][r] + bb1, 0.f));
          *reinterpret_cast<ushort*>(
              Xs + rowl * 256 + ((gg ^ (rowl & 7)) << 4) + cb) = hv;
        }
      }
    }
    LGKM0();
    __builtin_amdgcn_s_barrier();  // h1 visible
    FENCE();

    // ---- GEMM2: K=128; A=h1 (LDS), B=w2f (regs) ----
    f32x4 acc2[2] = {};
#pragma unroll
    for (int ks = 0; ks < 4; ks++) {
      int gk = ks * 4 + grp;
#pragma unroll
      for (int fm = 0; fm < 2; fm++) {
        int row = fm * 16 + l15;
        short8 af = *reinterpret_cast<const short8*>(
            Xs + row * 256 + ((gk ^ (row & 7)) << 4));
        acc2[fm] = __builtin_amdgcn_mfma_f32_16x16x32_bf16(af, w2f[ks],
                                                           acc2[fm], 0, 0, 0);
      }
    }

    // ---- epi2: wn<4 -> p8 (fp8 byte), wn>=4 -> s2 (f32 + b2) ----
#pragma unroll
    for (int fm = 0; fm < 2; fm++) {
#pragma unroll
      for (int r = 0; r < 4; r++) {
        int rowg = tile * 32 + fm * 16 + grp * 4 + r;
        if (rowg >= M) continue;
        if (colg < 64) {
          float v = acc2[fm][r];
          int b8 = __builtin_amdgcn_cvt_pk_fp8_f32(v, v, 0, false);
          P8[(size_t)rowg * 64 + colg] = (uchar)(b8 & 0xff);
        } else {
          S2[(size_t)rowg * 64 + (colg - 64)] = acc2[fm][r] + bb2;
        }
      }
    }

    if (!more) break;
    __builtin_amdgcn_s_barrier();  // h1 reads done (WAR before X overwrite)
    FENCE();
    WRITEX();
    LGKM0();
    __builtin_amdgcn_s_barrier();  // X(next) visible
    FENCE();
    tile = next;
  }
#undef LOADX
#undef WRITEX
}

extern "C" void kernel_launch(void* const* d_in, const int* in_sizes, int n_in,
                              void* d_out, int out_size, void* d_ws, size_t ws_size,
                              hipStream_t stream) {
  const float* h = (const float*)d_in[0];
  const int* esrc = (const int*)d_in[1];
  const int* edst = (const int*)d_in[2];
  const float* Ws1 = (const float*)d_in[3];
  const float* Wn1 = (const float*)d_in[4];
  const float* b1 = (const float*)d_in[5];
  const float* Ws2 = (const float*)d_in[6];
  const float* Wn2 = (const float*)d_in[7];
  const float* b2 = (const float*)d_in[8];
  float* out = (float*)d_out;

  const int N = in_sizes[0] / 128;  // 100000
  const int E = in_sizes[1];        // 1600000
  const int P = (N + 255) >> 8;     // 391 buckets (<=512)

  char* base = (char*)d_ws;
  size_t off = 0;
  auto alloc = [&](size_t bytes) {
    size_t o = off;
    off += (bytes + 255) & ~(size_t)255;
    return o;
  };
  int* deg = (int*)(base + alloc((size_t)N * 4));
  int* rs = (int*)(base + alloc((size_t)N * 4));
  int* bcnt = (int*)(base + alloc(513 * 4));
  int* bbase = (int*)(base + alloc(513 * 4));
  int* bcur = (int*)(base + alloc(513 * 4));
  uint* bed = (uint*)(base + alloc((size_t)E * 4));
  int* col = (int*)(base + alloc((size_t)E * 4));
  ushort* hb = (ushort*)(base + alloc((size_t)N * 128 * 2));
  uchar* h8 = (uchar*)(base + alloc((size_t)N * 128));
  ushort* aggb = (ushort*)(base + alloc((size_t)N * 128 * 2));
  ushort* Wt1 = (ushort*)(base + alloc(128 * 256 * 2));
  ushort* Wt2cat = (ushort*)(base + alloc(128 * 128 * 2));
  // overlays:
  uchar* p8 = (uchar*)bed;   // [N][64] fp8: bed dead after k_bcsr; N*64 <= E*4
  float* s2f = (float*)aggb; // [N][64] f32: row ranges owned by the writing tile

  const int NCH = (E + 4095) / 4096;  // 391 edge chunks
  const int NT = (N + 31) / 32;       // 3125 M-tiles (BM=32)
  const int n8 = N * 128 / 8;
  const int CB = (n8 + 255) / 256;    // cast blocks
  const int WB = (128 * 256 + 128 * 128) / 256;  // 192 weight blocks

  (void)hipMemsetAsync(bcnt, 0, 513 * 4, stream);
  k_bhist<<<NCH, 256, 0, stream>>>(edst, bcnt, E);
  k_bscan<<<1, 512, 0, stream>>>(bcnt, bbase, bcur, P, E);
  k_bscatter<<<NCH, 256, 0, stream>>>(edst, esrc, bcur, bed, E, P);
  k_bcsr<<<P, 256, 0, stream>>>(bed, bbase, deg, rs, col, N);

  k_prep<<<CB + WB, 256, 0, stream>>>(h, Ws1, Wn1, Ws2, Wn2, hb, h8, Wt1,
                                      Wt2cat, n8, CB);

  // Layer 1 aggregate, then persistent fused GEMM1+GEMM2 -> p2 (fp8) + s2 (f32)
  k_agg1<<<(N + 31) / 32, 256, 0, stream>>>(h8, col, rs, deg, aggb, N);
  k_persist<<<512, 512, 0, stream>>>(hb, aggb, Wt1, Wt2cat, b1, b2, p8, s2f, N, NT);
  // Layer 2 fused gather + add + relu
  k_agg_out<<<(N + 63) / 64, 256, 0, stream>>>(p8, s2f, col, rs, deg, out, N);
}